// Round 4
// baseline (425.990 us; speedup 1.0000x reference)
//
#include <hip/hip_runtime.h>
#include <hip/hip_bf16.h>

#define NEG_SLOPE 0.2f
#define PARTS 8   // XCD count (m09); blockIdx%8 ~ XCD via round-robin dispatch

// ---------------------------------------------------------------- bf16 helpers
__device__ __forceinline__ float bf_lo(uint32_t u) { return __uint_as_float(u << 16); }
__device__ __forceinline__ float bf_hi(uint32_t u) { return __uint_as_float(u & 0xffff0000u); }
__device__ __forceinline__ unsigned short f2bf(float f) {
    uint32_t u = __float_as_uint(f);
    u += 0x7fffu + ((u >> 16) & 1u);   // round-to-nearest-even
    return (unsigned short)(u >> 16);
}

// ---------------------------------------------------------------- CSR build (XCD-partitioned)
// Each block owns dst-partition p = blockIdx%8 -> counts/cursor/col writes stay
// in one XCD's L2 (full lines accumulate before writeback). Edge list re-read
// 8x but it is coalesced and L3-resident.
__global__ __launch_bounds__(256) void hist_part_kernel(const int* __restrict__ dst,
        int* __restrict__ counts, int E, int PS) {
    int p  = blockIdx.x & (PARTS - 1);
    int lo = p * PS, hi = lo + PS;
    int idx    = (blockIdx.x >> 3) * blockDim.x + threadIdx.x;
    int stride = (gridDim.x  >> 3) * blockDim.x;
    for (int e = idx; e < E; e += stride) {
        int d = dst[e];
        if (d >= lo && d < hi) atomicAdd(&counts[d], 1);
    }
}

// single-block exclusive scan: counts[N] -> row_ptr[N+1], cursor copy
__global__ void scan_kernel(const int* __restrict__ counts, int* __restrict__ row_ptr,
                            int* __restrict__ cursor, int N) {
    __shared__ int wsum[16];
    __shared__ int carry_s;
    int tid = threadIdx.x, lane = tid & 63, wid = tid >> 6;
    if (tid == 0) carry_s = 0;
    __syncthreads();
    for (int base = 0; base < N; base += 1024) {
        int i = base + tid;
        int v = (i < N) ? counts[i] : 0;
        int x = v;
        #pragma unroll
        for (int off = 1; off < 64; off <<= 1) {
            int t = __shfl_up(x, off);
            if (lane >= off) x += t;
        }
        if (lane == 63) wsum[wid] = x;
        __syncthreads();
        if (wid == 0 && lane < 16) {
            int w = wsum[lane];
            int inc = w;
            #pragma unroll
            for (int off = 1; off < 16; off <<= 1) {
                int t = __shfl_up(inc, off);
                if (lane >= off) inc += t;
            }
            wsum[lane] = inc - w;
        }
        __syncthreads();
        int excl = carry_s + wsum[wid] + x - v;
        if (i < N) { row_ptr[i] = excl; cursor[i] = excl; }
        __syncthreads();
        if (tid == 1023) carry_s += wsum[15] + x;
        __syncthreads();
    }
    if (threadIdx.x == 0) row_ptr[N] = carry_s;
}

// cursor holds absolute positions (pre-initialized to row_ptr); col is u16 (N<65536)
__global__ __launch_bounds__(256) void scatter_part_kernel(const int* __restrict__ src,
        const int* __restrict__ dst, int* __restrict__ cursor,
        unsigned short* __restrict__ colw, int E, int PS) {
    int p  = blockIdx.x & (PARTS - 1);
    int lo = p * PS, hi = lo + PS;
    int idx    = (blockIdx.x >> 3) * blockDim.x + threadIdx.x;
    int stride = (gridDim.x  >> 3) * blockDim.x;
    for (int e = idx; e < E; e += stride) {
        int d = dst[e];
        if (d >= lo && d < hi) {
            int pos = atomicAdd(&cursor[d], 1);
            colw[pos] = (unsigned short)src[e];
        }
    }
}

// ---------------------------------------------------------------- GEMM (fp32 in, fp32 or bf16 out)
template<int FIN, int FOUT, int ROWS, bool BF16OUT>
__global__ __launch_bounds__(256) void gemm_kernel(const float* __restrict__ X,
                                                   const float* __restrict__ W,
                                                   void* __restrict__ Hout, int N) {
    constexpr int TPR = 256 / ROWS;
    constexpr int CPT = FOUT / TPR;
    constexpr int NG  = CPT / 4;
    constexpr int XS  = FIN + 4;
    static_assert(CPT % 4 == 0, "CPT must be multiple of 4");
    __shared__ float sW[FIN * FOUT];
    __shared__ float sX[ROWS * XS];
    int tid = threadIdx.x;
    for (int i = tid * 4; i < FIN * FOUT; i += 1024)
        *(float4*)&sW[i] = *(const float4*)&W[i];
    int row0 = blockIdx.x * ROWS;
    for (int i = tid * 4; i < ROWS * FIN; i += 1024) {
        int r = i / FIN, k = i % FIN;
        int gr = row0 + r;
        float4 v = make_float4(0.f, 0.f, 0.f, 0.f);
        if (gr < N) v = *(const float4*)&X[(size_t)gr * FIN + k];
        *(float4*)&sX[r * XS + k] = v;
    }
    __syncthreads();
    int r  = tid / TPR;
    int cb = (tid % TPR) * 4;
    float4 acc[NG];
    #pragma unroll
    for (int g = 0; g < NG; ++g) acc[g] = make_float4(0.f, 0.f, 0.f, 0.f);
    const float* xrow = &sX[r * XS];
    for (int k = 0; k < FIN; ++k) {
        float xv = xrow[k];
        #pragma unroll
        for (int g = 0; g < NG; ++g) {
            float4 w = *(const float4*)&sW[k * FOUT + cb + g * (TPR * 4)];
            acc[g].x += xv * w.x; acc[g].y += xv * w.y;
            acc[g].z += xv * w.z; acc[g].w += xv * w.w;
        }
    }
    int gr = row0 + r;
    if (gr < N) {
        #pragma unroll
        for (int g = 0; g < NG; ++g) {
            size_t idx = (size_t)gr * FOUT + cb + g * (TPR * 4);
            if (BF16OUT) {
                ushort4 o;
                o.x = f2bf(acc[g].x); o.y = f2bf(acc[g].y);
                o.z = f2bf(acc[g].z); o.w = f2bf(acc[g].w);
                *(ushort4*)((unsigned short*)Hout + idx) = o;
            } else {
                *(float4*)((float*)Hout + idx) = acc[g];
            }
        }
    }
}

// small layer-3 GEMM: [N,64] @ [64,2] (fp32)
__global__ void gemm3_kernel(const float* __restrict__ X, const float* __restrict__ W,
                             float* __restrict__ Hout, int N) {
    int n = blockIdx.x * blockDim.x + threadIdx.x;
    if (n >= N) return;
    float a0 = 0.f, a1 = 0.f;
    const float4* xr = (const float4*)(X + (size_t)n * 64);
    #pragma unroll
    for (int k4 = 0; k4 < 16; ++k4) {
        float4 x = xr[k4];
        int k = k4 * 4;
        a0 += x.x * W[(k + 0) * 2] + x.y * W[(k + 1) * 2] + x.z * W[(k + 2) * 2] + x.w * W[(k + 3) * 2];
        a1 += x.x * W[(k + 0) * 2 + 1] + x.y * W[(k + 1) * 2 + 1] + x.z * W[(k + 2) * 2 + 1] + x.w * W[(k + 3) * 2 + 1];
    }
    Hout[n * 2 + 0] = a0;
    Hout[n * 2 + 1] = a1;
}

// ---------------------------------------------------------------- attention dots
template<int H, int C>
__global__ void attn_bf16_kernel(const unsigned short* __restrict__ Hb,
                                 const float* __restrict__ att_s, const float* __restrict__ att_d,
                                 float* __restrict__ a_src, float* __restrict__ a_dst, int N) {
    int t = blockIdx.x * blockDim.x + threadIdx.x;
    int n = t / H, h = t % H;
    if (n >= N) return;
    const uint32_t* row = (const uint32_t*)(Hb + (size_t)n * H * C + h * C);
    float as = 0.f, ad = 0.f;
    #pragma unroll
    for (int c2 = 0; c2 < C / 2; ++c2) {
        uint32_t p = row[c2];
        float v0 = bf_lo(p), v1 = bf_hi(p);
        as += v0 * att_s[h * C + c2 * 2] + v1 * att_s[h * C + c2 * 2 + 1];
        ad += v0 * att_d[h * C + c2 * 2] + v1 * att_d[h * C + c2 * 2 + 1];
    }
    a_src[n * H + h] = as;
    a_dst[n * H + h] = ad;
}

template<int H, int C>
__global__ void attn_kernel(const float* __restrict__ Hm, const float* __restrict__ att_s,
                            const float* __restrict__ att_d, float* __restrict__ a_src,
                            float* __restrict__ a_dst, int N) {
    int t = blockIdx.x * blockDim.x + threadIdx.x;
    int n = t / H, h = t % H;
    if (n >= N) return;
    const float* row = Hm + (size_t)n * H * C + h * C;
    float as = 0.f, ad = 0.f;
    for (int c = 0; c < C; ++c) {
        float v = row[c];
        as += v * att_s[h * C + c];
        ad += v * att_d[h * C + c];
    }
    a_src[n * H + h] = as;
    a_dst[n * H + h] = ad;
}

// ---------------------------------------------------------------- fused aggregation (bf16 h)
// One wave per dst node. Single pass, no max-subtraction (shift c=max(a_dst,0)
// bounds the exp argument; softmax is shift-invariant so result is exact).
template<int H, int C, bool ELU>
__global__ __launch_bounds__(256) void agg_fused_kernel(
        const unsigned short* __restrict__ Hb, const float* __restrict__ a_src,
        const float* __restrict__ a_dst, const int* __restrict__ row_ptr,
        const unsigned short* __restrict__ colw, const float* __restrict__ bias,
        float* __restrict__ out, int N) {
    constexpr int HC  = H * C;
    constexpr int LPE = HC / 2;       // lanes (pairs) per edge
    constexpr int EPI = 64 / LPE;     // edges per inner iteration (1 or 2)
    constexpr int SHIFT = (HC == 128) ? 8 : 7;   // log2(HC * sizeof(bf16))
    static_assert(HC == 128 || HC == 64, "layout");
    __shared__ float sP[4][64 * H];
    __shared__ int   sS[4][64];
    int wv   = threadIdx.x >> 6;
    int lane = threadIdx.x & 63;
    int n = (int)(blockIdx.x * 4 + wv);
    if (n >= N) return;
    int start = row_ptr[n];
    int deg   = row_ptr[n + 1] - start;

    float adv[H], cc[H], sp[H];
    #pragma unroll
    for (int h = 0; h < H; ++h) {
        adv[h] = a_dst[n * H + h];
        cc[h]  = fmaxf(adv[h], 0.f);
        sp[h]  = 0.f;
    }

    int sub = lane / LPE, pl = lane % LPE;
    int elem0 = pl * 2;
    int hh = elem0 / C;
    uint32_t boff = (uint32_t)(elem0 * 2);
    float acc0 = 0.f, acc1 = 0.f;

    for (int base = 0; base <= deg; base += 64) {
        int cnt = min(64, deg + 1 - base);
        int idx = base + lane;
        if (idx <= deg) {
            int src = (idx < deg) ? (int)colw[start + idx] : n;
            sS[wv][lane] = src;
            float av[H];
            if constexpr (H == 4) {
                float4 t = *(const float4*)&a_src[src * 4];
                av[0] = t.x; av[1] = t.y; av[2] = t.z; av[3] = t.w;
            } else {
                float2 t = *(const float2*)&a_src[src * 2];
                av[0] = t.x; av[1] = t.y;
            }
            #pragma unroll
            for (int h = 0; h < H; ++h) {
                float e = av[h] + adv[h];
                e = (e >= 0.f) ? e : NEG_SLOPE * e;
                float p = __expf(e - cc[h]);
                sp[h] += p;
                sP[wv][lane * H + h] = p;
            }
        }
        __threadfence_block();   // LDS writes visible before reads (same wave, lockstep)
        #pragma unroll 4
        for (int k = 0; k < cnt; k += EPI) {
            int eidx = k + sub;
            int eclm = (EPI == 2) ? min(eidx, cnt - 1) : eidx;
            float w  = sP[wv][eclm * H + hh];
            int  src = sS[wv][eclm];
            if (EPI == 2 && eidx >= cnt) w = 0.f;
            uint32_t off = ((uint32_t)src << SHIFT) + boff;
            uint32_t pv = *(const uint32_t*)((const char*)Hb + off);
            acc0 = fmaf(w, bf_lo(pv), acc0);
            acc1 = fmaf(w, bf_hi(pv), acc1);
        }
        __threadfence_block();   // reads done before next chunk overwrites
    }

    #pragma unroll
    for (int off = 32; off; off >>= 1) {
        #pragma unroll
        for (int h = 0; h < H; ++h) sp[h] += __shfl_xor(sp[h], off);
    }
    if constexpr (EPI == 2) {
        acc0 += __shfl_xor(acc0, 32);
        acc1 += __shfl_xor(acc1, 32);
    }
    if (sub == 0) {
        float inv = 1.f / sp[hh];
        float2 b = *(const float2*)&bias[elem0];
        float v0 = acc0 * inv + b.x;
        float v1 = acc1 * inv + b.y;
        if (ELU) {
            v0 = (v0 > 0.f) ? v0 : __expf(v0) - 1.f;
            v1 = (v1 > 0.f) ? v1 : __expf(v1) - 1.f;
        }
        *(float2*)&out[(size_t)n * HC + elem0] = make_float2(v0, v1);
    }
}

// layer 3: H=1, C=2, fp32, single-pass + bias + log_softmax -> d_out
__global__ __launch_bounds__(256) void agg3_kernel(
        const float* __restrict__ Hm, const float* __restrict__ a_src,
        const float* __restrict__ a_dst, const int* __restrict__ row_ptr,
        const unsigned short* __restrict__ colw, const float* __restrict__ bias,
        float* __restrict__ out, int N) {
    int wave = (int)((blockIdx.x * blockDim.x + threadIdx.x) >> 6);
    int lane = threadIdx.x & 63;
    if (wave >= N) return;
    int n = wave;
    int start = row_ptr[n];
    int deg   = row_ptr[n + 1] - start;
    float adv = a_dst[n];
    float c   = fmaxf(adv, 0.f);
    float s = 0.f, acc0 = 0.f, acc1 = 0.f;
    for (int i = lane; i <= deg; i += 64) {
        int src = (i < deg) ? (int)colw[start + i] : n;
        float e = a_src[src] + adv;
        e = (e >= 0.f) ? e : NEG_SLOPE * e;
        float p = __expf(e - c);
        float2 hv = *(const float2*)&Hm[src * 2];
        s += p;
        acc0 = fmaf(p, hv.x, acc0);
        acc1 = fmaf(p, hv.y, acc1);
    }
    #pragma unroll
    for (int off = 32; off; off >>= 1) {
        s    += __shfl_xor(s, off);
        acc0 += __shfl_xor(acc0, off);
        acc1 += __shfl_xor(acc1, off);
    }
    if (lane == 0) {
        float v0 = acc0 / s + bias[0];
        float v1 = acc1 / s + bias[1];
        float mx = fmaxf(v0, v1);
        float lse = mx + logf(__expf(v0 - mx) + __expf(v1 - mx));
        out[n * 2 + 0] = v0 - lse;
        out[n * 2 + 1] = v1 - lse;
    }
}

// ---------------------------------------------------------------- launch
extern "C" void kernel_launch(void* const* d_in, const int* in_sizes, int n_in,
                              void* d_out, int out_size, void* d_ws, size_t ws_size,
                              hipStream_t stream) {
    const float* x   = (const float*)d_in[0];
    const int*   ei  = (const int*)d_in[1];
    const float* W1  = (const float*)d_in[2];
    const float* as1 = (const float*)d_in[3];
    const float* ad1 = (const float*)d_in[4];
    const float* b1  = (const float*)d_in[5];
    const float* W2  = (const float*)d_in[6];
    const float* as2 = (const float*)d_in[7];
    const float* ad2 = (const float*)d_in[8];
    const float* b2  = (const float*)d_in[9];
    const float* W3  = (const float*)d_in[10];
    const float* as3 = (const float*)d_in[11];
    const float* ad3 = (const float*)d_in[12];
    const float* b3  = (const float*)d_in[13];
    int N = in_sizes[0] / 128;
    int E = in_sizes[1] / 2;
    const int* src = ei;
    const int* dst = ei + E;
    int PS = (N + PARTS - 1) / PARTS;   // dst-partition size (N=50000 < 65536 -> u16 col)

    char* ws = (char*)d_ws;
    size_t off = 0;
    auto alloc = [&](size_t bytes) -> void* {
        void* p = ws + off;
        off = (off + bytes + 255) & ~(size_t)255;
        return p;
    };
    int*            counts  = (int*)alloc((size_t)N * 4);
    int*            row_ptr = (int*)alloc((size_t)(N + 1) * 4);
    int*            cursor  = (int*)alloc((size_t)N * 4);
    unsigned short* colw    = (unsigned short*)alloc((size_t)E * 2);
    unsigned short* hb      = (unsigned short*)alloc((size_t)N * 128 * 2);
    float*          obuf    = (float*)alloc((size_t)N * 128 * 4);
    float*          h3      = (float*)alloc((size_t)N * 2 * 4);
    float*          asrc    = (float*)alloc((size_t)N * 4 * 4);
    float*          adst    = (float*)alloc((size_t)N * 4 * 4);

    // CSR by dst (XCD-partitioned hist + scatter)
    hipMemsetAsync(counts, 0, (size_t)N * 4, stream);
    hist_part_kernel<<<PARTS * 64, 256, 0, stream>>>(dst, counts, E, PS);
    scan_kernel<<<1, 1024, 0, stream>>>(counts, row_ptr, cursor, N);
    scatter_part_kernel<<<PARTS * 64, 256, 0, stream>>>(src, dst, cursor, colw, E, PS);

    // layer 1: 128 -> 4x32 (concat), elu
    gemm_kernel<128, 128, 16, true><<<(N + 15) / 16, 256, 0, stream>>>(x, W1, hb, N);
    attn_bf16_kernel<4, 32><<<(N * 4 + 255) / 256, 256, 0, stream>>>(hb, as1, ad1, asrc, adst, N);
    agg_fused_kernel<4, 32, true><<<(N + 3) / 4, 256, 0, stream>>>(hb, asrc, adst, row_ptr, colw, b1, obuf, N);

    // layer 2: 128 -> 2x32 (concat), elu
    gemm_kernel<128, 64, 16, true><<<(N + 15) / 16, 256, 0, stream>>>(obuf, W2, hb, N);
    attn_bf16_kernel<2, 32><<<(N * 2 + 255) / 256, 256, 0, stream>>>(hb, as2, ad2, asrc, adst, N);
    agg_fused_kernel<2, 32, true><<<(N + 3) / 4, 256, 0, stream>>>(hb, asrc, adst, row_ptr, colw, b2, obuf, N);

    // layer 3: 64 -> 2, 1 head, bias, log_softmax
    gemm3_kernel<<<(N + 255) / 256, 256, 0, stream>>>(obuf, W3, h3, N);
    attn_kernel<1, 2><<<(N + 255) / 256, 256, 0, stream>>>(h3, as3, ad3, asrc, adst, N);
    agg3_kernel<<<(N + 3) / 4, 256, 0, stream>>>(h3, asrc, adst, row_ptr, colw, b3, (float*)d_out, N);
}

// Round 5
// 280.382 us; speedup vs baseline: 1.5193x; 1.5193x over previous
//
#include <hip/hip_runtime.h>
#include <hip/hip_bf16.h>

#define NEG_SLOPE 0.2f

// ---------------------------------------------------------------- bf16 helpers
__device__ __forceinline__ float bf_lo(uint32_t u) { return __uint_as_float(u << 16); }
__device__ __forceinline__ float bf_hi(uint32_t u) { return __uint_as_float(u & 0xffff0000u); }
__device__ __forceinline__ unsigned short f2bf(float f) {
    uint32_t u = __float_as_uint(f);
    u += 0x7fffu + ((u >> 16) & 1u);   // round-to-nearest-even
    return (unsigned short)(u >> 16);
}

// ---------------------------------------------------------------- CSR build via 2-level bucket sort
// bucket = dst>>8 (196 used for N=50000). All scatter writes are contiguous
// per-writer; pass 3 is fully block-local (one block per bucket).

// pass 1: coarse bucket counts
__global__ __launch_bounds__(256) void bkt_count_kernel(const int* __restrict__ dst,
                                                        int* __restrict__ bcnt, int E) {
    __shared__ int lh[256];
    lh[threadIdx.x] = 0;
    __syncthreads();
    int idx = blockIdx.x * blockDim.x + threadIdx.x;
    int stride = gridDim.x * blockDim.x;
    for (int e = idx; e < E; e += stride)
        atomicAdd(&lh[dst[e] >> 8], 1);
    __syncthreads();
    if (lh[threadIdx.x]) atomicAdd(&bcnt[threadIdx.x], lh[threadIdx.x]);
}

// tiny scan over 256 buckets -> base[257]; cursor=base; row_ptr[N]=E
__global__ void bkt_scan_kernel(const int* __restrict__ bcnt, int* __restrict__ bbase,
                                int* __restrict__ bcur, int* __restrict__ row_ptr,
                                int N, int E) {
    int tid = threadIdx.x, lane = tid & 63, wid = tid >> 6;
    __shared__ int ws4[4];
    int v = bcnt[tid];
    int x = v;
    #pragma unroll
    for (int off = 1; off < 64; off <<= 1) {
        int t = __shfl_up(x, off);
        if (lane >= off) x += t;
    }
    if (lane == 63) ws4[wid] = x;
    __syncthreads();
    int add = 0;
    #pragma unroll
    for (int w = 0; w < 4; ++w) if (w < wid) add += ws4[w];
    int excl = add + x - v;
    bbase[tid] = excl;
    bcur[tid]  = excl;
    if (tid == 255) { bbase[256] = excl + v; row_ptr[N] = E; }
}

// pass 2: chunked scatter into bucket arenas; packed = (dst&255)<<16 | src
__global__ __launch_bounds__(256) void bkt_scatter_kernel(const int* __restrict__ src,
        const int* __restrict__ dst, int* __restrict__ bcur,
        uint32_t* __restrict__ packed, int E) {
    __shared__ int lh[256], lbase[256], lcur[256];
    int tid = threadIdx.x;
    lh[tid] = 0; lcur[tid] = 0;
    __syncthreads();
    int chunk = (E + gridDim.x - 1) / gridDim.x;
    int e0 = blockIdx.x * chunk;
    int e1 = min(E, e0 + chunk);
    for (int e = e0 + tid; e < e1; e += 256)
        atomicAdd(&lh[dst[e] >> 8], 1);
    __syncthreads();
    if (lh[tid]) lbase[tid] = atomicAdd(&bcur[tid], lh[tid]);
    __syncthreads();
    for (int e = e0 + tid; e < e1; e += 256) {
        int d = dst[e];
        int b = d >> 8;
        int pos = lbase[b] + atomicAdd(&lcur[b], 1);
        packed[pos] = ((uint32_t)(d & 255) << 16) | (uint32_t)src[e];
    }
}

// pass 3: one block per bucket — counting sort by low byte, block-local writes.
// Also emits row_ptr[d] = seg0 + excl[d&255] (replaces hist+scan kernels).
__global__ __launch_bounds__(256) void bkt_sort_kernel(const uint32_t* __restrict__ packed,
        const int* __restrict__ bbase, int* __restrict__ row_ptr,
        unsigned short* __restrict__ colw, int N) {
    __shared__ int lh[256], lexcl[256], lcur[256];
    __shared__ int ws4[4];
    int tid = threadIdx.x, lane = tid & 63, wid = tid >> 6;
    int B = blockIdx.x;
    int seg0 = bbase[B], seg1 = bbase[B + 1];
    lh[tid] = 0; lcur[tid] = 0;
    __syncthreads();
    for (int i = seg0 + tid; i < seg1; i += 256)
        atomicAdd(&lh[packed[i] >> 16], 1);
    __syncthreads();
    int v = lh[tid];
    int x = v;
    #pragma unroll
    for (int off = 1; off < 64; off <<= 1) {
        int t = __shfl_up(x, off);
        if (lane >= off) x += t;
    }
    if (lane == 63) ws4[wid] = x;
    __syncthreads();
    int add = 0;
    #pragma unroll
    for (int w = 0; w < 4; ++w) if (w < wid) add += ws4[w];
    int excl = add + x - v;
    lexcl[tid] = excl;
    int d = B * 256 + tid;
    if (d < N) row_ptr[d] = seg0 + excl;
    __syncthreads();
    for (int i = seg0 + tid; i < seg1; i += 256) {
        uint32_t p = packed[i];
        int bin = p >> 16;
        int pos = seg0 + lexcl[bin] + atomicAdd(&lcur[bin], 1);
        colw[pos] = (unsigned short)(p & 0xFFFF);
    }
}

// ---------------------------------------------------------------- GEMM (fp32 in, fp32 or bf16 out)
template<int FIN, int FOUT, int ROWS, bool BF16OUT>
__global__ __launch_bounds__(256) void gemm_kernel(const float* __restrict__ X,
                                                   const float* __restrict__ W,
                                                   void* __restrict__ Hout, int N) {
    constexpr int TPR = 256 / ROWS;
    constexpr int CPT = FOUT / TPR;
    constexpr int NG  = CPT / 4;
    constexpr int XS  = FIN + 4;
    static_assert(CPT % 4 == 0, "CPT must be multiple of 4");
    __shared__ float sW[FIN * FOUT];
    __shared__ float sX[ROWS * XS];
    int tid = threadIdx.x;
    for (int i = tid * 4; i < FIN * FOUT; i += 1024)
        *(float4*)&sW[i] = *(const float4*)&W[i];
    int row0 = blockIdx.x * ROWS;
    for (int i = tid * 4; i < ROWS * FIN; i += 1024) {
        int r = i / FIN, k = i % FIN;
        int gr = row0 + r;
        float4 v = make_float4(0.f, 0.f, 0.f, 0.f);
        if (gr < N) v = *(const float4*)&X[(size_t)gr * FIN + k];
        *(float4*)&sX[r * XS + k] = v;
    }
    __syncthreads();
    int r  = tid / TPR;
    int cb = (tid % TPR) * 4;
    float4 acc[NG];
    #pragma unroll
    for (int g = 0; g < NG; ++g) acc[g] = make_float4(0.f, 0.f, 0.f, 0.f);
    const float* xrow = &sX[r * XS];
    for (int k = 0; k < FIN; ++k) {
        float xv = xrow[k];
        #pragma unroll
        for (int g = 0; g < NG; ++g) {
            float4 w = *(const float4*)&sW[k * FOUT + cb + g * (TPR * 4)];
            acc[g].x += xv * w.x; acc[g].y += xv * w.y;
            acc[g].z += xv * w.z; acc[g].w += xv * w.w;
        }
    }
    int gr = row0 + r;
    if (gr < N) {
        #pragma unroll
        for (int g = 0; g < NG; ++g) {
            size_t idx = (size_t)gr * FOUT + cb + g * (TPR * 4);
            if (BF16OUT) {
                ushort4 o;
                o.x = f2bf(acc[g].x); o.y = f2bf(acc[g].y);
                o.z = f2bf(acc[g].z); o.w = f2bf(acc[g].w);
                *(ushort4*)((unsigned short*)Hout + idx) = o;
            } else {
                *(float4*)((float*)Hout + idx) = acc[g];
            }
        }
    }
}

// small layer-3 GEMM: [N,64] @ [64,2] (fp32)
__global__ void gemm3_kernel(const float* __restrict__ X, const float* __restrict__ W,
                             float* __restrict__ Hout, int N) {
    int n = blockIdx.x * blockDim.x + threadIdx.x;
    if (n >= N) return;
    float a0 = 0.f, a1 = 0.f;
    const float4* xr = (const float4*)(X + (size_t)n * 64);
    #pragma unroll
    for (int k4 = 0; k4 < 16; ++k4) {
        float4 x = xr[k4];
        int k = k4 * 4;
        a0 += x.x * W[(k + 0) * 2] + x.y * W[(k + 1) * 2] + x.z * W[(k + 2) * 2] + x.w * W[(k + 3) * 2];
        a1 += x.x * W[(k + 0) * 2 + 1] + x.y * W[(k + 1) * 2 + 1] + x.z * W[(k + 2) * 2 + 1] + x.w * W[(k + 3) * 2 + 1];
    }
    Hout[n * 2 + 0] = a0;
    Hout[n * 2 + 1] = a1;
}

// ---------------------------------------------------------------- attention dots
template<int H, int C>
__global__ void attn_bf16_kernel(const unsigned short* __restrict__ Hb,
                                 const float* __restrict__ att_s, const float* __restrict__ att_d,
                                 float* __restrict__ a_src, float* __restrict__ a_dst, int N) {
    int t = blockIdx.x * blockDim.x + threadIdx.x;
    int n = t / H, h = t % H;
    if (n >= N) return;
    const uint32_t* row = (const uint32_t*)(Hb + (size_t)n * H * C + h * C);
    float as = 0.f, ad = 0.f;
    #pragma unroll
    for (int c2 = 0; c2 < C / 2; ++c2) {
        uint32_t p = row[c2];
        float v0 = bf_lo(p), v1 = bf_hi(p);
        as += v0 * att_s[h * C + c2 * 2] + v1 * att_s[h * C + c2 * 2 + 1];
        ad += v0 * att_d[h * C + c2 * 2] + v1 * att_d[h * C + c2 * 2 + 1];
    }
    a_src[n * H + h] = as;
    a_dst[n * H + h] = ad;
}

template<int H, int C>
__global__ void attn_kernel(const float* __restrict__ Hm, const float* __restrict__ att_s,
                            const float* __restrict__ att_d, float* __restrict__ a_src,
                            float* __restrict__ a_dst, int N) {
    int t = blockIdx.x * blockDim.x + threadIdx.x;
    int n = t / H, h = t % H;
    if (n >= N) return;
    const float* row = Hm + (size_t)n * H * C + h * C;
    float as = 0.f, ad = 0.f;
    for (int c = 0; c < C; ++c) {
        float v = row[c];
        as += v * att_s[h * C + c];
        ad += v * att_d[h * C + c];
    }
    a_src[n * H + h] = as;
    a_dst[n * H + h] = ad;
}

// ---------------------------------------------------------------- fused aggregation (bf16 h)
// One wave per dst node. Single pass, no max-subtraction (shift c=max(a_dst,0)
// bounds the exp argument; softmax is shift-invariant so result is exact).
template<int H, int C, bool ELU>
__global__ __launch_bounds__(256) void agg_fused_kernel(
        const unsigned short* __restrict__ Hb, const float* __restrict__ a_src,
        const float* __restrict__ a_dst, const int* __restrict__ row_ptr,
        const unsigned short* __restrict__ colw, const float* __restrict__ bias,
        float* __restrict__ out, int N) {
    constexpr int HC  = H * C;
    constexpr int LPE = HC / 2;       // lanes (pairs) per edge
    constexpr int EPI = 64 / LPE;     // edges per inner iteration (1 or 2)
    constexpr int SHIFT = (HC == 128) ? 8 : 7;   // log2(HC * sizeof(bf16))
    static_assert(HC == 128 || HC == 64, "layout");
    __shared__ float sP[4][64 * H];
    __shared__ int   sS[4][64];
    int wv   = threadIdx.x >> 6;
    int lane = threadIdx.x & 63;
    int n = (int)(blockIdx.x * 4 + wv);
    if (n >= N) return;
    int start = row_ptr[n];
    int deg   = row_ptr[n + 1] - start;

    float adv[H], cc[H], sp[H];
    #pragma unroll
    for (int h = 0; h < H; ++h) {
        adv[h] = a_dst[n * H + h];
        cc[h]  = fmaxf(adv[h], 0.f);
        sp[h]  = 0.f;
    }

    int sub = lane / LPE, pl = lane % LPE;
    int elem0 = pl * 2;
    int hh = elem0 / C;
    uint32_t boff = (uint32_t)(elem0 * 2);
    float acc0 = 0.f, acc1 = 0.f;

    for (int base = 0; base <= deg; base += 64) {
        int cnt = min(64, deg + 1 - base);
        int idx = base + lane;
        if (idx <= deg) {
            int src = (idx < deg) ? (int)colw[start + idx] : n;
            sS[wv][lane] = src;
            float av[H];
            if constexpr (H == 4) {
                float4 t = *(const float4*)&a_src[src * 4];
                av[0] = t.x; av[1] = t.y; av[2] = t.z; av[3] = t.w;
            } else {
                float2 t = *(const float2*)&a_src[src * 2];
                av[0] = t.x; av[1] = t.y;
            }
            #pragma unroll
            for (int h = 0; h < H; ++h) {
                float e = av[h] + adv[h];
                e = (e >= 0.f) ? e : NEG_SLOPE * e;
                float p = __expf(e - cc[h]);
                sp[h] += p;
                sP[wv][lane * H + h] = p;
            }
        }
        __threadfence_block();   // LDS writes visible before reads (same wave, lockstep)
        #pragma unroll 4
        for (int k = 0; k < cnt; k += EPI) {
            int eidx = k + sub;
            int eclm = (EPI == 2) ? min(eidx, cnt - 1) : eidx;
            float w  = sP[wv][eclm * H + hh];
            int  src = sS[wv][eclm];
            if (EPI == 2 && eidx >= cnt) w = 0.f;
            uint32_t off = ((uint32_t)src << SHIFT) + boff;
            uint32_t pv = *(const uint32_t*)((const char*)Hb + off);
            acc0 = fmaf(w, bf_lo(pv), acc0);
            acc1 = fmaf(w, bf_hi(pv), acc1);
        }
        __threadfence_block();   // reads done before next chunk overwrites
    }

    #pragma unroll
    for (int off = 32; off; off >>= 1) {
        #pragma unroll
        for (int h = 0; h < H; ++h) sp[h] += __shfl_xor(sp[h], off);
    }
    if constexpr (EPI == 2) {
        acc0 += __shfl_xor(acc0, 32);
        acc1 += __shfl_xor(acc1, 32);
    }
    if (sub == 0) {
        float inv = 1.f / sp[hh];
        float2 b = *(const float2*)&bias[elem0];
        float v0 = acc0 * inv + b.x;
        float v1 = acc1 * inv + b.y;
        if (ELU) {
            v0 = (v0 > 0.f) ? v0 : __expf(v0) - 1.f;
            v1 = (v1 > 0.f) ? v1 : __expf(v1) - 1.f;
        }
        *(float2*)&out[(size_t)n * HC + elem0] = make_float2(v0, v1);
    }
}

// layer 3: H=1, C=2, fp32, single-pass + bias + log_softmax -> d_out
__global__ __launch_bounds__(256) void agg3_kernel(
        const float* __restrict__ Hm, const float* __restrict__ a_src,
        const float* __restrict__ a_dst, const int* __restrict__ row_ptr,
        const unsigned short* __restrict__ colw, const float* __restrict__ bias,
        float* __restrict__ out, int N) {
    int wave = (int)((blockIdx.x * blockDim.x + threadIdx.x) >> 6);
    int lane = threadIdx.x & 63;
    if (wave >= N) return;
    int n = wave;
    int start = row_ptr[n];
    int deg   = row_ptr[n + 1] - start;
    float adv = a_dst[n];
    float c   = fmaxf(adv, 0.f);
    float s = 0.f, acc0 = 0.f, acc1 = 0.f;
    for (int i = lane; i <= deg; i += 64) {
        int src = (i < deg) ? (int)colw[start + i] : n;
        float e = a_src[src] + adv;
        e = (e >= 0.f) ? e : NEG_SLOPE * e;
        float p = __expf(e - c);
        float2 hv = *(const float2*)&Hm[src * 2];
        s += p;
        acc0 = fmaf(p, hv.x, acc0);
        acc1 = fmaf(p, hv.y, acc1);
    }
    #pragma unroll
    for (int off = 32; off; off >>= 1) {
        s    += __shfl_xor(s, off);
        acc0 += __shfl_xor(acc0, off);
        acc1 += __shfl_xor(acc1, off);
    }
    if (lane == 0) {
        float v0 = acc0 / s + bias[0];
        float v1 = acc1 / s + bias[1];
        float mx = fmaxf(v0, v1);
        float lse = mx + logf(__expf(v0 - mx) + __expf(v1 - mx));
        out[n * 2 + 0] = v0 - lse;
        out[n * 2 + 1] = v1 - lse;
    }
}

// ---------------------------------------------------------------- launch
extern "C" void kernel_launch(void* const* d_in, const int* in_sizes, int n_in,
                              void* d_out, int out_size, void* d_ws, size_t ws_size,
                              hipStream_t stream) {
    const float* x   = (const float*)d_in[0];
    const int*   ei  = (const int*)d_in[1];
    const float* W1  = (const float*)d_in[2];
    const float* as1 = (const float*)d_in[3];
    const float* ad1 = (const float*)d_in[4];
    const float* b1  = (const float*)d_in[5];
    const float* W2  = (const float*)d_in[6];
    const float* as2 = (const float*)d_in[7];
    const float* ad2 = (const float*)d_in[8];
    const float* b2  = (const float*)d_in[9];
    const float* W3  = (const float*)d_in[10];
    const float* as3 = (const float*)d_in[11];
    const float* ad3 = (const float*)d_in[12];
    const float* b3  = (const float*)d_in[13];
    int N = in_sizes[0] / 128;
    int E = in_sizes[1] / 2;
    const int* src = ei;
    const int* dst = ei + E;
    int NB = (N + 255) / 256;           // used buckets

    char* ws = (char*)d_ws;
    size_t off = 0;
    auto alloc = [&](size_t bytes) -> void* {
        void* p = ws + off;
        off = (off + bytes + 255) & ~(size_t)255;
        return p;
    };
    int*            bcnt    = (int*)alloc(256 * 4);
    int*            bbase   = (int*)alloc(257 * 4);
    int*            bcur    = (int*)alloc(256 * 4);
    int*            row_ptr = (int*)alloc((size_t)(N + 1) * 4);
    uint32_t*       packed  = (uint32_t*)alloc((size_t)E * 4);
    unsigned short* colw    = (unsigned short*)alloc((size_t)E * 2);
    unsigned short* hb      = (unsigned short*)alloc((size_t)N * 128 * 2);
    float*          obuf    = (float*)alloc((size_t)N * 128 * 4);
    float*          h3      = (float*)alloc((size_t)N * 2 * 4);
    float*          asrc    = (float*)alloc((size_t)N * 4 * 4);
    float*          adst    = (float*)alloc((size_t)N * 4 * 4);

    // CSR by dst via 2-level bucket sort (no cross-block write sharing)
    hipMemsetAsync(bcnt, 0, 256 * 4, stream);
    bkt_count_kernel<<<256, 256, 0, stream>>>(dst, bcnt, E);
    bkt_scan_kernel<<<1, 256, 0, stream>>>(bcnt, bbase, bcur, row_ptr, N, E);
    bkt_scatter_kernel<<<256, 256, 0, stream>>>(src, dst, bcur, packed, E);
    bkt_sort_kernel<<<NB, 256, 0, stream>>>(packed, bbase, row_ptr, colw, N);

    // layer 1: 128 -> 4x32 (concat), elu
    gemm_kernel<128, 128, 16, true><<<(N + 15) / 16, 256, 0, stream>>>(x, W1, hb, N);
    attn_bf16_kernel<4, 32><<<(N * 4 + 255) / 256, 256, 0, stream>>>(hb, as1, ad1, asrc, adst, N);
    agg_fused_kernel<4, 32, true><<<(N + 3) / 4, 256, 0, stream>>>(hb, asrc, adst, row_ptr, colw, b1, obuf, N);

    // layer 2: 128 -> 2x32 (concat), elu
    gemm_kernel<128, 64, 16, true><<<(N + 15) / 16, 256, 0, stream>>>(obuf, W2, hb, N);
    attn_bf16_kernel<2, 32><<<(N * 2 + 255) / 256, 256, 0, stream>>>(hb, as2, ad2, asrc, adst, N);
    agg_fused_kernel<2, 32, true><<<(N + 3) / 4, 256, 0, stream>>>(hb, asrc, adst, row_ptr, colw, b2, obuf, N);

    // layer 3: 64 -> 2, 1 head, bias, log_softmax
    gemm3_kernel<<<(N + 255) / 256, 256, 0, stream>>>(obuf, W3, h3, N);
    attn_kernel<1, 2><<<(N + 255) / 256, 256, 0, stream>>>(h3, as3, ad3, asrc, adst, N);
    agg3_kernel<<<(N + 3) / 4, 256, 0, stream>>>(h3, asrc, adst, row_ptr, colw, b3, (float*)d_out, N);
}

// Round 6
// 243.500 us; speedup vs baseline: 1.7494x; 1.1515x over previous
//
#include <hip/hip_runtime.h>
#include <hip/hip_bf16.h>

#define NEG_SLOPE 0.2f

#if __has_builtin(__builtin_amdgcn_mfma_f32_16x16x32_bf16)
#define HAVE_MFMA 1
#else
#define HAVE_MFMA 0
#endif

typedef __attribute__((ext_vector_type(8))) short short8v;
typedef __attribute__((ext_vector_type(4))) float f32x4;

// ---------------------------------------------------------------- bf16 helpers
__device__ __forceinline__ float bf_lo(uint32_t u) { return __uint_as_float(u << 16); }
__device__ __forceinline__ float bf_hi(uint32_t u) { return __uint_as_float(u & 0xffff0000u); }
__device__ __forceinline__ unsigned short f2bf(float f) {
    uint32_t u = __float_as_uint(f);
    u += 0x7fffu + ((u >> 16) & 1u);   // round-to-nearest-even
    return (unsigned short)(u >> 16);
}
__device__ __forceinline__ float bf2f(unsigned short h) {
    return __uint_as_float((uint32_t)h << 16);
}

// assumed (lane,reg)->k maps for mfma_f32_16x16x32_bf16 A/B operands.
// lay 1: two CDNA3-style K=16 halves; lay 2: contiguous 8.
// NOTE: any k-permutation applied consistently to BOTH A and B cancels in the
// contraction, so only the row/col lane-maps (lane&15) truly matter. The probe
// verifies the joint hypothesis against the HW-verified C/D layout (m89).
__device__ __forceinline__ int k_of(int lay, int l, int j) {
    return (lay == 1) ? ((l >> 4) * 4 + (j & 3) + 16 * (j >> 2))
                      : ((l >> 4) * 8 + j);
}

// probe: exact integer test; writes 1/2 (accepted layout) or 0 (fallback fp32)
__global__ void mfma_probe_kernel(int* flag) {
#if HAVE_MFMA
    int l = threadIdx.x;
    for (int lay = 1; lay <= 2; ++lay) {
        short8v a, b;
        #pragma unroll
        for (int j = 0; j < 8; ++j) {
            int k = k_of(lay, l, j);
            a[j] = (short)f2bf((float)(2 * (l & 15) + 5 * k));
            int n = l & 15;
            float bv = (k == n) ? 1.f : ((k == n + 16) ? 2.f : 0.f);
            b[j] = (short)f2bf(bv);
        }
        f32x4 c = {0.f, 0.f, 0.f, 0.f};
        c = __builtin_amdgcn_mfma_f32_16x16x32_bf16(a, b, c, 0, 0, 0);
        bool good = true;
        #pragma unroll
        for (int r = 0; r < 4; ++r) {
            int row = (l >> 4) * 4 + r, col = l & 15;
            if (c[r] != (float)(6 * row + 15 * col + 160)) good = false;
        }
        if (__all(good)) { if (l == 0) *flag = lay; return; }
    }
    if (l == 0) *flag = 0;
#else
    if (threadIdx.x == 0) *flag = 0;
#endif
}

// pack W[FIN][FOUT] into fragment order: [plane(hi/lo)][q][nt][lane][j] bf16
template<int FIN, int FOUT>
__global__ void packW_kernel(const float* __restrict__ W, unsigned short* __restrict__ Wp,
                             const int* __restrict__ flag) {
    int lay = *flag;
    if (lay == 0) return;
    constexpr int NT = FOUT / 16, KC = FIN / 32;
    int tid = blockIdx.x * blockDim.x + threadIdx.x;
    if (tid >= KC * NT * 64) return;
    int l  = tid & 63;
    int nt = (tid >> 6) % NT;
    int q  = tid / (64 * NT);
    int n  = nt * 16 + (l & 15);
    #pragma unroll
    for (int j = 0; j < 8; ++j) {
        int k = q * 32 + k_of(lay, l, j);
        float v = W[k * FOUT + n];
        unsigned short h = f2bf(v);
        unsigned short lo = f2bf(v - bf2f(h));
        Wp[(((size_t)0 * KC + q) * NT + nt) * 512 + l * 8 + j] = h;
        Wp[(((size_t)1 * KC + q) * NT + nt) * 512 + l * 8 + j] = lo;
    }
}

// MFMA GEMM: X[N][FIN] fp32 -> Hout[N][FOUT] bf16, split-bf16 x3 (~fp32 exact)
template<int FIN, int FOUT>
__global__ __launch_bounds__(256) void gemm_mfma_kernel(const float* __restrict__ X,
        const unsigned short* __restrict__ Wp, unsigned short* __restrict__ Hout,
        const int* __restrict__ flag, int N) {
#if HAVE_MFMA
    int lay = *flag;
    if (lay == 0) return;
    constexpr int NT = FOUT / 16, KC = FIN / 32;
    __shared__ float sX[4][16 * FIN];
    int wv = threadIdx.x >> 6, l = threadIdx.x & 63;
    int mtile = blockIdx.x * 4 + wv;
    if (mtile * 16 >= N) return;          // N % 16 == 0 for this problem
    const float* xsrc = X + (size_t)mtile * 16 * FIN;
    float* lds = sX[wv];
    #pragma unroll
    for (int i = 0; i < (16 * FIN) / 256; ++i) {
        int fi = (i * 64 + l) * 4;
        *(float4*)&lds[fi] = *(const float4*)&xsrc[fi];
    }
    __threadfence_block();   // same-wave cross-lane LDS visibility

    int koff[8];
    #pragma unroll
    for (int j = 0; j < 8; ++j) koff[j] = k_of(lay, l, j);
    int arow = (l & 15) * FIN;

    f32x4 acc[NT];
    #pragma unroll
    for (int nt = 0; nt < NT; ++nt) acc[nt] = f32x4{0.f, 0.f, 0.f, 0.f};

    const short8v* wp8 = (const short8v*)Wp;
    for (int q = 0; q < KC; ++q) {
        short8v ahi, alo;
        #pragma unroll
        for (int j = 0; j < 8; ++j) {
            float v = lds[arow + q * 32 + koff[j]];
            unsigned short h = f2bf(v);
            ahi[j] = (short)h;
            alo[j] = (short)f2bf(v - bf2f(h));
        }
        #pragma unroll
        for (int nt = 0; nt < NT; ++nt) {
            short8v bhi = wp8[((0 * KC + q) * NT + nt) * 64 + l];
            short8v blo = wp8[((1 * KC + q) * NT + nt) * 64 + l];
            acc[nt] = __builtin_amdgcn_mfma_f32_16x16x32_bf16(ahi, bhi, acc[nt], 0, 0, 0);
            acc[nt] = __builtin_amdgcn_mfma_f32_16x16x32_bf16(alo, bhi, acc[nt], 0, 0, 0);
            acc[nt] = __builtin_amdgcn_mfma_f32_16x16x32_bf16(ahi, blo, acc[nt], 0, 0, 0);
        }
    }
    int row0 = mtile * 16 + (l >> 4) * 4;
    int col  = l & 15;
    #pragma unroll
    for (int nt = 0; nt < NT; ++nt)
        #pragma unroll
        for (int r = 0; r < 4; ++r)
            Hout[(size_t)(row0 + r) * FOUT + nt * 16 + col] = f2bf(acc[nt][r]);
#endif
}

// ---------------------------------------------------------------- CSR build via 2-level bucket sort
__global__ __launch_bounds__(256) void bkt_count_kernel(const int* __restrict__ dst,
                                                        int* __restrict__ bcnt, int E) {
    __shared__ int lh[256];
    lh[threadIdx.x] = 0;
    __syncthreads();
    int idx = blockIdx.x * blockDim.x + threadIdx.x;
    int stride = gridDim.x * blockDim.x;
    for (int e = idx; e < E; e += stride)
        atomicAdd(&lh[dst[e] >> 8], 1);
    __syncthreads();
    if (lh[threadIdx.x]) atomicAdd(&bcnt[threadIdx.x], lh[threadIdx.x]);
}

__global__ void bkt_scan_kernel(const int* __restrict__ bcnt, int* __restrict__ bbase,
                                int* __restrict__ bcur, int* __restrict__ row_ptr,
                                int N, int E) {
    int tid = threadIdx.x, lane = tid & 63, wid = tid >> 6;
    __shared__ int ws4[4];
    int v = bcnt[tid];
    int x = v;
    #pragma unroll
    for (int off = 1; off < 64; off <<= 1) {
        int t = __shfl_up(x, off);
        if (lane >= off) x += t;
    }
    if (lane == 63) ws4[wid] = x;
    __syncthreads();
    int add = 0;
    #pragma unroll
    for (int w = 0; w < 4; ++w) if (w < wid) add += ws4[w];
    int excl = add + x - v;
    bbase[tid] = excl;
    bcur[tid]  = excl;
    if (tid == 255) { bbase[256] = excl + v; row_ptr[N] = E; }
}

__global__ __launch_bounds__(256) void bkt_scatter_kernel(const int* __restrict__ src,
        const int* __restrict__ dst, int* __restrict__ bcur,
        uint32_t* __restrict__ packed, int E) {
    __shared__ int lh[256], lbase[256], lcur[256];
    int tid = threadIdx.x;
    lh[tid] = 0; lcur[tid] = 0;
    __syncthreads();
    int chunk = (E + gridDim.x - 1) / gridDim.x;
    int e0 = blockIdx.x * chunk;
    int e1 = min(E, e0 + chunk);
    for (int e = e0 + tid; e < e1; e += 256)
        atomicAdd(&lh[dst[e] >> 8], 1);
    __syncthreads();
    if (lh[tid]) lbase[tid] = atomicAdd(&bcur[tid], lh[tid]);
    __syncthreads();
    for (int e = e0 + tid; e < e1; e += 256) {
        int d = dst[e];
        int b = d >> 8;
        int pos = lbase[b] + atomicAdd(&lcur[b], 1);
        packed[pos] = ((uint32_t)(d & 255) << 16) | (uint32_t)src[e];
    }
}

__global__ __launch_bounds__(256) void bkt_sort_kernel(const uint32_t* __restrict__ packed,
        const int* __restrict__ bbase, int* __restrict__ row_ptr,
        unsigned short* __restrict__ colw, int N) {
    __shared__ int lh[256], lexcl[256], lcur[256];
    __shared__ int ws4[4];
    int tid = threadIdx.x, lane = tid & 63, wid = tid >> 6;
    int B = blockIdx.x;
    int seg0 = bbase[B], seg1 = bbase[B + 1];
    lh[tid] = 0; lcur[tid] = 0;
    __syncthreads();
    for (int i = seg0 + tid; i < seg1; i += 256)
        atomicAdd(&lh[packed[i] >> 16], 1);
    __syncthreads();
    int v = lh[tid];
    int x = v;
    #pragma unroll
    for (int off = 1; off < 64; off <<= 1) {
        int t = __shfl_up(x, off);
        if (lane >= off) x += t;
    }
    if (lane == 63) ws4[wid] = x;
    __syncthreads();
    int add = 0;
    #pragma unroll
    for (int w = 0; w < 4; ++w) if (w < wid) add += ws4[w];
    int excl = add + x - v;
    lexcl[tid] = excl;
    int d = B * 256 + tid;
    if (d < N) row_ptr[d] = seg0 + excl;
    __syncthreads();
    for (int i = seg0 + tid; i < seg1; i += 256) {
        uint32_t p = packed[i];
        int bin = p >> 16;
        int pos = seg0 + lexcl[bin] + atomicAdd(&lcur[bin], 1);
        colw[pos] = (unsigned short)(p & 0xFFFF);
    }
}

// ---------------------------------------------------------------- fp32 GEMM (fallback, runs iff flag==0)
template<int FIN, int FOUT, int ROWS, bool BF16OUT>
__global__ __launch_bounds__(256) void gemm_kernel(const float* __restrict__ X,
                                                   const float* __restrict__ W,
                                                   void* __restrict__ Hout,
                                                   const int* __restrict__ flag, int N) {
    if (*flag != 0) return;   // uniform across block; MFMA path active
    constexpr int TPR = 256 / ROWS;
    constexpr int CPT = FOUT / TPR;
    constexpr int NG  = CPT / 4;
    constexpr int XS  = FIN + 4;
    static_assert(CPT % 4 == 0, "CPT must be multiple of 4");
    __shared__ float sW[FIN * FOUT];
    __shared__ float sX[ROWS * XS];
    int tid = threadIdx.x;
    for (int i = tid * 4; i < FIN * FOUT; i += 1024)
        *(float4*)&sW[i] = *(const float4*)&W[i];
    int row0 = blockIdx.x * ROWS;
    for (int i = tid * 4; i < ROWS * FIN; i += 1024) {
        int r = i / FIN, k = i % FIN;
        int gr = row0 + r;
        float4 v = make_float4(0.f, 0.f, 0.f, 0.f);
        if (gr < N) v = *(const float4*)&X[(size_t)gr * FIN + k];
        *(float4*)&sX[r * XS + k] = v;
    }
    __syncthreads();
    int r  = tid / TPR;
    int cb = (tid % TPR) * 4;
    float4 acc[NG];
    #pragma unroll
    for (int g = 0; g < NG; ++g) acc[g] = make_float4(0.f, 0.f, 0.f, 0.f);
    const float* xrow = &sX[r * XS];
    for (int k = 0; k < FIN; ++k) {
        float xv = xrow[k];
        #pragma unroll
        for (int g = 0; g < NG; ++g) {
            float4 w = *(const float4*)&sW[k * FOUT + cb + g * (TPR * 4)];
            acc[g].x += xv * w.x; acc[g].y += xv * w.y;
            acc[g].z += xv * w.z; acc[g].w += xv * w.w;
        }
    }
    int gr = row0 + r;
    if (gr < N) {
        #pragma unroll
        for (int g = 0; g < NG; ++g) {
            size_t idx = (size_t)gr * FOUT + cb + g * (TPR * 4);
            if (BF16OUT) {
                ushort4 o;
                o.x = f2bf(acc[g].x); o.y = f2bf(acc[g].y);
                o.z = f2bf(acc[g].z); o.w = f2bf(acc[g].w);
                *(ushort4*)((unsigned short*)Hout + idx) = o;
            } else {
                *(float4*)((float*)Hout + idx) = acc[g];
            }
        }
    }
}

// small layer-3 GEMM: [N,64] @ [64,2] (fp32)
__global__ void gemm3_kernel(const float* __restrict__ X, const float* __restrict__ W,
                             float* __restrict__ Hout, int N) {
    int n = blockIdx.x * blockDim.x + threadIdx.x;
    if (n >= N) return;
    float a0 = 0.f, a1 = 0.f;
    const float4* xr = (const float4*)(X + (size_t)n * 64);
    #pragma unroll
    for (int k4 = 0; k4 < 16; ++k4) {
        float4 x = xr[k4];
        int k = k4 * 4;
        a0 += x.x * W[(k + 0) * 2] + x.y * W[(k + 1) * 2] + x.z * W[(k + 2) * 2] + x.w * W[(k + 3) * 2];
        a1 += x.x * W[(k + 0) * 2 + 1] + x.y * W[(k + 1) * 2 + 1] + x.z * W[(k + 2) * 2 + 1] + x.w * W[(k + 3) * 2 + 1];
    }
    Hout[n * 2 + 0] = a0;
    Hout[n * 2 + 1] = a1;
}

// ---------------------------------------------------------------- attention dots
template<int H, int C>
__global__ void attn_bf16_kernel(const unsigned short* __restrict__ Hb,
                                 const float* __restrict__ att_s, const float* __restrict__ att_d,
                                 float* __restrict__ a_src, float* __restrict__ a_dst, int N) {
    int t = blockIdx.x * blockDim.x + threadIdx.x;
    int n = t / H, h = t % H;
    if (n >= N) return;
    const uint32_t* row = (const uint32_t*)(Hb + (size_t)n * H * C + h * C);
    float as = 0.f, ad = 0.f;
    #pragma unroll
    for (int c2 = 0; c2 < C / 2; ++c2) {
        uint32_t p = row[c2];
        float v0 = bf_lo(p), v1 = bf_hi(p);
        as += v0 * att_s[h * C + c2 * 2] + v1 * att_s[h * C + c2 * 2 + 1];
        ad += v0 * att_d[h * C + c2 * 2] + v1 * att_d[h * C + c2 * 2 + 1];
    }
    a_src[n * H + h] = as;
    a_dst[n * H + h] = ad;
}

template<int H, int C>
__global__ void attn_kernel(const float* __restrict__ Hm, const float* __restrict__ att_s,
                            const float* __restrict__ att_d, float* __restrict__ a_src,
                            float* __restrict__ a_dst, int N) {
    int t = blockIdx.x * blockDim.x + threadIdx.x;
    int n = t / H, h = t % H;
    if (n >= N) return;
    const float* row = Hm + (size_t)n * H * C + h * C;
    float as = 0.f, ad = 0.f;
    for (int c = 0; c < C; ++c) {
        float v = row[c];
        as += v * att_s[h * C + c];
        ad += v * att_d[h * C + c];
    }
    a_src[n * H + h] = as;
    a_dst[n * H + h] = ad;
}

// ---------------------------------------------------------------- fused aggregation (bf16 h)
template<int H, int C, bool ELU>
__global__ __launch_bounds__(256) void agg_fused_kernel(
        const unsigned short* __restrict__ Hb, const float* __restrict__ a_src,
        const float* __restrict__ a_dst, const int* __restrict__ row_ptr,
        const unsigned short* __restrict__ colw, const float* __restrict__ bias,
        float* __restrict__ out, int N) {
    constexpr int HC  = H * C;
    constexpr int LPE = HC / 2;
    constexpr int EPI = 64 / LPE;
    constexpr int SHIFT = (HC == 128) ? 8 : 7;
    static_assert(HC == 128 || HC == 64, "layout");
    __shared__ float sP[4][64 * H];
    __shared__ int   sS[4][64];
    int wv   = threadIdx.x >> 6;
    int lane = threadIdx.x & 63;
    int n = (int)(blockIdx.x * 4 + wv);
    if (n >= N) return;
    int start = row_ptr[n];
    int deg   = row_ptr[n + 1] - start;

    float adv[H], cc[H], sp[H];
    #pragma unroll
    for (int h = 0; h < H; ++h) {
        adv[h] = a_dst[n * H + h];
        cc[h]  = fmaxf(adv[h], 0.f);
        sp[h]  = 0.f;
    }

    int sub = lane / LPE, pl = lane % LPE;
    int elem0 = pl * 2;
    int hh = elem0 / C;
    uint32_t boff = (uint32_t)(elem0 * 2);
    float acc0 = 0.f, acc1 = 0.f;

    for (int base = 0; base <= deg; base += 64) {
        int cnt = min(64, deg + 1 - base);
        int idx = base + lane;
        if (idx <= deg) {
            int src = (idx < deg) ? (int)colw[start + idx] : n;
            sS[wv][lane] = src;
            float av[H];
            if constexpr (H == 4) {
                float4 t = *(const float4*)&a_src[src * 4];
                av[0] = t.x; av[1] = t.y; av[2] = t.z; av[3] = t.w;
            } else {
                float2 t = *(const float2*)&a_src[src * 2];
                av[0] = t.x; av[1] = t.y;
            }
            #pragma unroll
            for (int h = 0; h < H; ++h) {
                float e = av[h] + adv[h];
                e = (e >= 0.f) ? e : NEG_SLOPE * e;
                float p = __expf(e - cc[h]);
                sp[h] += p;
                sP[wv][lane * H + h] = p;
            }
        }
        __threadfence_block();
        #pragma unroll 4
        for (int k = 0; k < cnt; k += EPI) {
            int eidx = k + sub;
            int eclm = (EPI == 2) ? min(eidx, cnt - 1) : eidx;
            float w  = sP[wv][eclm * H + hh];
            int  src = sS[wv][eclm];
            if (EPI == 2 && eidx >= cnt) w = 0.f;
            uint32_t off = ((uint32_t)src << SHIFT) + boff;
            uint32_t pv = *(const uint32_t*)((const char*)Hb + off);
            acc0 = fmaf(w, bf_lo(pv), acc0);
            acc1 = fmaf(w, bf_hi(pv), acc1);
        }
        __threadfence_block();
    }

    #pragma unroll
    for (int off = 32; off; off >>= 1) {
        #pragma unroll
        for (int h = 0; h < H; ++h) sp[h] += __shfl_xor(sp[h], off);
    }
    if constexpr (EPI == 2) {
        acc0 += __shfl_xor(acc0, 32);
        acc1 += __shfl_xor(acc1, 32);
    }
    if (sub == 0) {
        float inv = 1.f / sp[hh];
        float2 b = *(const float2*)&bias[elem0];
        float v0 = acc0 * inv + b.x;
        float v1 = acc1 * inv + b.y;
        if (ELU) {
            v0 = (v0 > 0.f) ? v0 : __expf(v0) - 1.f;
            v1 = (v1 > 0.f) ? v1 : __expf(v1) - 1.f;
        }
        *(float2*)&out[(size_t)n * HC + elem0] = make_float2(v0, v1);
    }
}

// layer 3: H=1, C=2, fp32, single-pass + bias + log_softmax -> d_out
__global__ __launch_bounds__(256) void agg3_kernel(
        const float* __restrict__ Hm, const float* __restrict__ a_src,
        const float* __restrict__ a_dst, const int* __restrict__ row_ptr,
        const unsigned short* __restrict__ colw, const float* __restrict__ bias,
        float* __restrict__ out, int N) {
    int wave = (int)((blockIdx.x * blockDim.x + threadIdx.x) >> 6);
    int lane = threadIdx.x & 63;
    if (wave >= N) return;
    int n = wave;
    int start = row_ptr[n];
    int deg   = row_ptr[n + 1] - start;
    float adv = a_dst[n];
    float c   = fmaxf(adv, 0.f);
    float s = 0.f, acc0 = 0.f, acc1 = 0.f;
    for (int i = lane; i <= deg; i += 64) {
        int src = (i < deg) ? (int)colw[start + i] : n;
        float e = a_src[src] + adv;
        e = (e >= 0.f) ? e : NEG_SLOPE * e;
        float p = __expf(e - c);
        float2 hv = *(const float2*)&Hm[src * 2];
        s += p;
        acc0 = fmaf(p, hv.x, acc0);
        acc1 = fmaf(p, hv.y, acc1);
    }
    #pragma unroll
    for (int off = 32; off; off >>= 1) {
        s    += __shfl_xor(s, off);
        acc0 += __shfl_xor(acc0, off);
        acc1 += __shfl_xor(acc1, off);
    }
    if (lane == 0) {
        float v0 = acc0 / s + bias[0];
        float v1 = acc1 / s + bias[1];
        float mx = fmaxf(v0, v1);
        float lse = mx + logf(__expf(v0 - mx) + __expf(v1 - mx));
        out[n * 2 + 0] = v0 - lse;
        out[n * 2 + 1] = v1 - lse;
    }
}

// ---------------------------------------------------------------- launch
extern "C" void kernel_launch(void* const* d_in, const int* in_sizes, int n_in,
                              void* d_out, int out_size, void* d_ws, size_t ws_size,
                              hipStream_t stream) {
    const float* x   = (const float*)d_in[0];
    const int*   ei  = (const int*)d_in[1];
    const float* W1  = (const float*)d_in[2];
    const float* as1 = (const float*)d_in[3];
    const float* ad1 = (const float*)d_in[4];
    const float* b1  = (const float*)d_in[5];
    const float* W2  = (const float*)d_in[6];
    const float* as2 = (const float*)d_in[7];
    const float* ad2 = (const float*)d_in[8];
    const float* b2  = (const float*)d_in[9];
    const float* W3  = (const float*)d_in[10];
    const float* as3 = (const float*)d_in[11];
    const float* ad3 = (const float*)d_in[12];
    const float* b3  = (const float*)d_in[13];
    int N = in_sizes[0] / 128;
    int E = in_sizes[1] / 2;
    const int* src = ei;
    const int* dst = ei + E;
    int NB = (N + 255) / 256;

    char* ws = (char*)d_ws;
    size_t off = 0;
    auto alloc = [&](size_t bytes) -> void* {
        void* p = ws + off;
        off = (off + bytes + 255) & ~(size_t)255;
        return p;
    };
    int*            bcnt    = (int*)alloc(256 * 4);
    int*            bbase   = (int*)alloc(257 * 4);
    int*            bcur    = (int*)alloc(256 * 4);
    int*            row_ptr = (int*)alloc((size_t)(N + 1) * 4);
    uint32_t*       packed  = (uint32_t*)alloc((size_t)E * 4);
    unsigned short* colw    = (unsigned short*)alloc((size_t)E * 2);
    unsigned short* hb      = (unsigned short*)alloc((size_t)N * 128 * 2);
    float*          obuf    = (float*)alloc((size_t)N * 128 * 4);
    float*          h3      = (float*)alloc((size_t)N * 2 * 4);
    float*          asrc    = (float*)alloc((size_t)N * 4 * 4);
    float*          adst    = (float*)alloc((size_t)N * 4 * 4);
    int*            mflag   = (int*)alloc(4);
    unsigned short* Wp1     = (unsigned short*)alloc((size_t)2 * 4 * 8 * 512 * 2);  // [2][KC=4][NT=8][512]
    unsigned short* Wp2     = (unsigned short*)alloc((size_t)2 * 4 * 4 * 512 * 2);  // [2][KC=4][NT=4][512]

    // MFMA layout probe + W fragment pre-pack
    mfma_probe_kernel<<<1, 64, 0, stream>>>(mflag);
    packW_kernel<128, 128><<<8, 256, 0, stream>>>(W1, Wp1, mflag);
    packW_kernel<128, 64><<<4, 256, 0, stream>>>(W2, Wp2, mflag);

    // CSR by dst via 2-level bucket sort
    hipMemsetAsync(bcnt, 0, 256 * 4, stream);
    bkt_count_kernel<<<256, 256, 0, stream>>>(dst, bcnt, E);
    bkt_scan_kernel<<<1, 256, 0, stream>>>(bcnt, bbase, bcur, row_ptr, N, E);
    bkt_scatter_kernel<<<256, 256, 0, stream>>>(src, dst, bcur, packed, E);
    bkt_sort_kernel<<<NB, 256, 0, stream>>>(packed, bbase, row_ptr, colw, N);

    int gmblocks = ((N + 15) / 16 + 3) / 4;

    // layer 1: 128 -> 4x32 (concat), elu
    gemm_mfma_kernel<128, 128><<<gmblocks, 256, 0, stream>>>(x, Wp1, hb, mflag, N);
    gemm_kernel<128, 128, 16, true><<<(N + 15) / 16, 256, 0, stream>>>(x, W1, hb, mflag, N);
    attn_bf16_kernel<4, 32><<<(N * 4 + 255) / 256, 256, 0, stream>>>(hb, as1, ad1, asrc, adst, N);
    agg_fused_kernel<4, 32, true><<<(N + 3) / 4, 256, 0, stream>>>(hb, asrc, adst, row_ptr, colw, b1, obuf, N);

    // layer 2: 128 -> 2x32 (concat), elu
    gemm_mfma_kernel<128, 64><<<gmblocks, 256, 0, stream>>>(obuf, Wp2, hb, mflag, N);
    gemm_kernel<128, 64, 16, true><<<(N + 15) / 16, 256, 0, stream>>>(obuf, W2, hb, mflag, N);
    attn_bf16_kernel<2, 32><<<(N * 2 + 255) / 256, 256, 0, stream>>>(hb, as2, ad2, asrc, adst, N);
    agg_fused_kernel<2, 32, true><<<(N + 3) / 4, 256, 0, stream>>>(hb, asrc, adst, row_ptr, colw, b2, obuf, N);

    // layer 3: 64 -> 2, 1 head, bias, log_softmax
    gemm3_kernel<<<(N + 255) / 256, 256, 0, stream>>>(obuf, W3, h3, N);
    attn_kernel<1, 2><<<(N + 255) / 256, 256, 0, stream>>>(h3, as3, ad3, asrc, adst, N);
    agg3_kernel<<<(N + 3) / 4, 256, 0, stream>>>(h3, asrc, adst, row_ptr, colw, b3, (float*)d_out, N);
}

// Round 7
// 221.456 us; speedup vs baseline: 1.9236x; 1.0995x over previous
//
#include <hip/hip_runtime.h>
#include <hip/hip_bf16.h>

#define NEG_SLOPE 0.2f

#if __has_builtin(__builtin_amdgcn_mfma_f32_16x16x32_bf16)
#define HAVE_MFMA 1
#else
#define HAVE_MFMA 0
#endif

typedef __attribute__((ext_vector_type(8))) short short8v;
typedef __attribute__((ext_vector_type(4))) float f32x4;

// ---------------------------------------------------------------- bf16 helpers
__device__ __forceinline__ float bf_lo(uint32_t u) { return __uint_as_float(u << 16); }
__device__ __forceinline__ float bf_hi(uint32_t u) { return __uint_as_float(u & 0xffff0000u); }
__device__ __forceinline__ unsigned short f2bf(float f) {
    uint32_t u = __float_as_uint(f);
    u += 0x7fffu + ((u >> 16) & 1u);   // round-to-nearest-even
    return (unsigned short)(u >> 16);
}
__device__ __forceinline__ float bf2f(unsigned short h) {
    return __uint_as_float((uint32_t)h << 16);
}

// assumed (lane,reg)->k maps for mfma_f32_16x16x32_bf16 A/B operands.
// Consistent A/B k-permutations cancel; probe verifies vs HW C/D layout (m89).
__device__ __forceinline__ int k_of(int lay, int l, int j) {
    return (lay == 1) ? ((l >> 4) * 4 + (j & 3) + 16 * (j >> 2))
                      : ((l >> 4) * 8 + j);
}

// probe: exact integer test; writes 1/2 (accepted layout) or 0 (fallback fp32)
__global__ void mfma_probe_kernel(int* flag) {
#if HAVE_MFMA
    int l = threadIdx.x;
    for (int lay = 1; lay <= 2; ++lay) {
        short8v a, b;
        #pragma unroll
        for (int j = 0; j < 8; ++j) {
            int k = k_of(lay, l, j);
            a[j] = (short)f2bf((float)(2 * (l & 15) + 5 * k));
            int n = l & 15;
            float bv = (k == n) ? 1.f : ((k == n + 16) ? 2.f : 0.f);
            b[j] = (short)f2bf(bv);
        }
        f32x4 c = {0.f, 0.f, 0.f, 0.f};
        c = __builtin_amdgcn_mfma_f32_16x16x32_bf16(a, b, c, 0, 0, 0);
        bool good = true;
        #pragma unroll
        for (int r = 0; r < 4; ++r) {
            int row = (l >> 4) * 4 + r, col = l & 15;
            if (c[r] != (float)(6 * row + 15 * col + 160)) good = false;
        }
        if (__all(good)) { if (l == 0) *flag = lay; return; }
    }
    if (l == 0) *flag = 0;
#else
    if (threadIdx.x == 0) *flag = 0;
#endif
}

// pack W[FIN][FOUT] into fragment order: [plane(hi/lo)][q][nt][lane][j] bf16
template<int FIN, int FOUT>
__global__ void packW_kernel(const float* __restrict__ W, unsigned short* __restrict__ Wp,
                             const int* __restrict__ flag) {
    int lay = *flag;
    if (lay == 0) return;
    constexpr int NT = FOUT / 16, KC = FIN / 32;
    int tid = blockIdx.x * blockDim.x + threadIdx.x;
    if (tid >= KC * NT * 64) return;
    int l  = tid & 63;
    int nt = (tid >> 6) % NT;
    int q  = tid / (64 * NT);
    int n  = nt * 16 + (l & 15);
    #pragma unroll
    for (int j = 0; j < 8; ++j) {
        int k = q * 32 + k_of(lay, l, j);
        float v = W[k * FOUT + n];
        unsigned short h = f2bf(v);
        unsigned short lo = f2bf(v - bf2f(h));
        Wp[(((size_t)0 * KC + q) * NT + nt) * 512 + l * 8 + j] = h;
        Wp[(((size_t)1 * KC + q) * NT + nt) * 512 + l * 8 + j] = lo;
    }
}

// MFMA GEMM + fused attention-dot epilogue. X fp32 -> Hout bf16; a_src/a_dst fp32.
template<int FIN, int FOUT, int H>
__global__ __launch_bounds__(256) void gemm_mfma_kernel(const float* __restrict__ X,
        const unsigned short* __restrict__ Wp, unsigned short* __restrict__ Hout,
        float* __restrict__ a_src, float* __restrict__ a_dst,
        const float* __restrict__ att_s, const float* __restrict__ att_d,
        const int* __restrict__ flag, int N) {
#if HAVE_MFMA
    int lay = *flag;
    if (lay == 0) return;
    constexpr int NT = FOUT / 16, KC = FIN / 32;
    __shared__ float sX[4][16 * FIN];
    int wv = threadIdx.x >> 6, l = threadIdx.x & 63;
    int mtile = blockIdx.x * 4 + wv;
    if (mtile * 16 >= N) return;          // N % 16 == 0 here
    const float* xsrc = X + (size_t)mtile * 16 * FIN;
    float* lds = sX[wv];
    #pragma unroll
    for (int i = 0; i < (16 * FIN) / 256; ++i) {
        int fi = (i * 64 + l) * 4;
        *(float4*)&lds[fi] = *(const float4*)&xsrc[fi];
    }
    __threadfence_block();

    int koff[8];
    #pragma unroll
    for (int j = 0; j < 8; ++j) koff[j] = k_of(lay, l, j);
    int arow = (l & 15) * FIN;

    f32x4 acc[NT];
    #pragma unroll
    for (int nt = 0; nt < NT; ++nt) acc[nt] = f32x4{0.f, 0.f, 0.f, 0.f};

    const short8v* wp8 = (const short8v*)Wp;
    for (int q = 0; q < KC; ++q) {
        short8v ahi, alo;
        #pragma unroll
        for (int j = 0; j < 8; ++j) {
            float v = lds[arow + q * 32 + koff[j]];
            unsigned short h = f2bf(v);
            ahi[j] = (short)h;
            alo[j] = (short)f2bf(v - bf2f(h));
        }
        #pragma unroll
        for (int nt = 0; nt < NT; ++nt) {
            short8v bhi = wp8[((0 * KC + q) * NT + nt) * 64 + l];
            short8v blo = wp8[((1 * KC + q) * NT + nt) * 64 + l];
            acc[nt] = __builtin_amdgcn_mfma_f32_16x16x32_bf16(ahi, bhi, acc[nt], 0, 0, 0);
            acc[nt] = __builtin_amdgcn_mfma_f32_16x16x32_bf16(alo, bhi, acc[nt], 0, 0, 0);
            acc[nt] = __builtin_amdgcn_mfma_f32_16x16x32_bf16(ahi, blo, acc[nt], 0, 0, 0);
        }
    }

    // epilogue 1: attention dots. Lane holds col (l&15) of NT tiles; head = nt>>1 (C=32).
    float as_v[NT], ad_v[NT];
    #pragma unroll
    for (int nt = 0; nt < NT; ++nt) {
        as_v[nt] = att_s[nt * 16 + (l & 15)];
        ad_v[nt] = att_d[nt * 16 + (l & 15)];
    }
    float ps[4][H], pd[4][H];
    #pragma unroll
    for (int r = 0; r < 4; ++r)
        #pragma unroll
        for (int h = 0; h < H; ++h) { ps[r][h] = 0.f; pd[r][h] = 0.f; }
    #pragma unroll
    for (int nt = 0; nt < NT; ++nt)
        #pragma unroll
        for (int r = 0; r < 4; ++r) {
            ps[r][nt >> 1] += acc[nt][r] * as_v[nt];
            pd[r][nt >> 1] += acc[nt][r] * ad_v[nt];
        }
    // transpose-reduce over the 16 lanes of each group via LDS scratch (reuse sX)
    constexpr int V = 4 * H;
    float* sc = lds;
    int g = l >> 4, l16 = l & 15;
    int base = g * 16 * V + l16 * V;
    __threadfence_block();   // all main-loop LDS reads complete (wave lockstep)
    #pragma unroll
    for (int r = 0; r < 4; ++r)
        #pragma unroll
        for (int h = 0; h < H; ++h) {
            sc[base + r * H + h]        = ps[r][h];
            sc[1024 + base + r * H + h] = pd[r][h];
        }
    __threadfence_block();
    if (l16 < V) {
        float S = 0.f, D = 0.f;
        #pragma unroll
        for (int x = 0; x < 16; ++x) {
            S += sc[g * 16 * V + x * V + l16];
            D += sc[1024 + g * 16 * V + x * V + l16];
        }
        int r = l16 / H, h = l16 % H;
        int row = mtile * 16 + g * 4 + r;
        a_src[row * H + h] = S;
        a_dst[row * H + h] = D;
    }

    // epilogue 2: bf16 H output
    int row0 = mtile * 16 + (l >> 4) * 4;
    int col  = l & 15;
    #pragma unroll
    for (int nt = 0; nt < NT; ++nt)
        #pragma unroll
        for (int r = 0; r < 4; ++r)
            Hout[(size_t)(row0 + r) * FOUT + nt * 16 + col] = f2bf(acc[nt][r]);
#endif
}

// ---------------------------------------------------------------- CSR build via 2-level bucket sort
__global__ __launch_bounds__(256) void bkt_count_kernel(const int* __restrict__ dst,
                                                        int* __restrict__ bcnt, int E) {
    __shared__ int lh[256];
    lh[threadIdx.x] = 0;
    __syncthreads();
    int idx = blockIdx.x * blockDim.x + threadIdx.x;
    int stride = gridDim.x * blockDim.x;
    for (int e = idx; e < E; e += stride)
        atomicAdd(&lh[dst[e] >> 8], 1);
    __syncthreads();
    if (lh[threadIdx.x]) atomicAdd(&bcnt[threadIdx.x], lh[threadIdx.x]);
}

__global__ void bkt_scan_kernel(const int* __restrict__ bcnt, int* __restrict__ bbase,
                                int* __restrict__ bcur, int* __restrict__ row_ptr,
                                int N, int E) {
    int tid = threadIdx.x, lane = tid & 63, wid = tid >> 6;
    __shared__ int ws4[4];
    int v = bcnt[tid];
    int x = v;
    #pragma unroll
    for (int off = 1; off < 64; off <<= 1) {
        int t = __shfl_up(x, off);
        if (lane >= off) x += t;
    }
    if (lane == 63) ws4[wid] = x;
    __syncthreads();
    int add = 0;
    #pragma unroll
    for (int w = 0; w < 4; ++w) if (w < wid) add += ws4[w];
    int excl = add + x - v;
    bbase[tid] = excl;
    bcur[tid]  = excl;
    if (tid == 255) { bbase[256] = excl + v; row_ptr[N] = E; }
}

__global__ __launch_bounds__(256) void bkt_scatter_kernel(const int* __restrict__ src,
        const int* __restrict__ dst, int* __restrict__ bcur,
        uint32_t* __restrict__ packed, int E) {
    __shared__ int lh[256], lbase[256], lcur[256];
    int tid = threadIdx.x;
    lh[tid] = 0; lcur[tid] = 0;
    __syncthreads();
    int chunk = (E + gridDim.x - 1) / gridDim.x;
    int e0 = blockIdx.x * chunk;
    int e1 = min(E, e0 + chunk);
    for (int e = e0 + tid; e < e1; e += 256)
        atomicAdd(&lh[dst[e] >> 8], 1);
    __syncthreads();
    if (lh[tid]) lbase[tid] = atomicAdd(&bcur[tid], lh[tid]);
    __syncthreads();
    for (int e = e0 + tid; e < e1; e += 256) {
        int d = dst[e];
        int b = d >> 8;
        int pos = lbase[b] + atomicAdd(&lcur[b], 1);
        packed[pos] = ((uint32_t)(d & 255) << 16) | (uint32_t)src[e];
    }
}

__global__ __launch_bounds__(256) void bkt_sort_kernel(const uint32_t* __restrict__ packed,
        const int* __restrict__ bbase, int* __restrict__ row_ptr,
        unsigned short* __restrict__ colw, int N) {
    __shared__ int lh[256], lexcl[256], lcur[256];
    __shared__ int ws4[4];
    int tid = threadIdx.x, lane = tid & 63, wid = tid >> 6;
    int B = blockIdx.x;
    int seg0 = bbase[B], seg1 = bbase[B + 1];
    lh[tid] = 0; lcur[tid] = 0;
    __syncthreads();
    for (int i = seg0 + tid; i < seg1; i += 256)
        atomicAdd(&lh[packed[i] >> 16], 1);
    __syncthreads();
    int v = lh[tid];
    int x = v;
    #pragma unroll
    for (int off = 1; off < 64; off <<= 1) {
        int t = __shfl_up(x, off);
        if (lane >= off) x += t;
    }
    if (lane == 63) ws4[wid] = x;
    __syncthreads();
    int add = 0;
    #pragma unroll
    for (int w = 0; w < 4; ++w) if (w < wid) add += ws4[w];
    int excl = add + x - v;
    lexcl[tid] = excl;
    int d = B * 256 + tid;
    if (d < N) row_ptr[d] = seg0 + excl;
    __syncthreads();
    for (int i = seg0 + tid; i < seg1; i += 256) {
        uint32_t p = packed[i];
        int bin = p >> 16;
        int pos = seg0 + lexcl[bin] + atomicAdd(&lcur[bin], 1);
        colw[pos] = (unsigned short)(p & 0xFFFF);
    }
}

// ---------------------------------------------------------------- fp32 GEMM fallback (runs iff flag==0), fused attn dots
template<int FIN, int FOUT, int ROWS, int H>
__global__ __launch_bounds__(256) void gemm_fb_kernel(const float* __restrict__ X,
        const float* __restrict__ W, unsigned short* __restrict__ Hout,
        float* __restrict__ a_src, float* __restrict__ a_dst,
        const float* __restrict__ att_s, const float* __restrict__ att_d,
        const int* __restrict__ flag, int N) {
    if (*flag != 0) return;
    constexpr int TPR = 256 / ROWS;
    constexpr int CPT = FOUT / TPR;
    constexpr int NG  = CPT / 4;
    constexpr int XS  = FIN + 4;
    static_assert(CPT % 4 == 0, "CPT must be multiple of 4");
    __shared__ float sW[FIN * FOUT];
    __shared__ float sX[ROWS * XS];
    int tid = threadIdx.x;
    for (int i = tid * 4; i < FIN * FOUT; i += 1024)
        *(float4*)&sW[i] = *(const float4*)&W[i];
    int row0 = blockIdx.x * ROWS;
    for (int i = tid * 4; i < ROWS * FIN; i += 1024) {
        int r = i / FIN, k = i % FIN;
        int gr = row0 + r;
        float4 v = make_float4(0.f, 0.f, 0.f, 0.f);
        if (gr < N) v = *(const float4*)&X[(size_t)gr * FIN + k];
        *(float4*)&sX[r * XS + k] = v;
    }
    __syncthreads();
    int r  = tid / TPR;
    int cb = (tid % TPR) * 4;
    float4 acc[NG];
    #pragma unroll
    for (int g = 0; g < NG; ++g) acc[g] = make_float4(0.f, 0.f, 0.f, 0.f);
    const float* xrow = &sX[r * XS];
    for (int k = 0; k < FIN; ++k) {
        float xv = xrow[k];
        #pragma unroll
        for (int g = 0; g < NG; ++g) {
            float4 w = *(const float4*)&sW[k * FOUT + cb + g * (TPR * 4)];
            acc[g].x += xv * w.x; acc[g].y += xv * w.y;
            acc[g].z += xv * w.z; acc[g].w += xv * w.w;
        }
    }
    // fused attention dots (16 threads per row are consecutive lanes)
    float ps0 = 0.f, ps1 = 0.f, ps2 = 0.f, ps3 = 0.f;
    float pd0 = 0.f, pd1 = 0.f, pd2 = 0.f, pd3 = 0.f;
    #pragma unroll
    for (int g = 0; g < NG; ++g) {
        int col0 = cb + g * (TPR * 4);
        const float* ap = (const float*)&acc[g];
        float s = 0.f, d = 0.f;
        #pragma unroll
        for (int j = 0; j < 4; ++j) { s += ap[j] * att_s[col0 + j]; d += ap[j] * att_d[col0 + j]; }
        int hg = col0 >> 5;   // 4 cols never cross a 32-col head
        if (hg == 0) { ps0 += s; pd0 += d; }
        else if (hg == 1) { ps1 += s; pd1 += d; }
        else if (H > 2 && hg == 2) { ps2 += s; pd2 += d; }
        else if (H > 2) { ps3 += s; pd3 += d; }
    }
    #pragma unroll
    for (int off = 1; off < 16; off <<= 1) {
        ps0 += __shfl_xor(ps0, off); ps1 += __shfl_xor(ps1, off);
        pd0 += __shfl_xor(pd0, off); pd1 += __shfl_xor(pd1, off);
        if (H > 2) {
            ps2 += __shfl_xor(ps2, off); ps3 += __shfl_xor(ps3, off);
            pd2 += __shfl_xor(pd2, off); pd3 += __shfl_xor(pd3, off);
        }
    }
    int gr = row0 + r;
    int l16 = tid % TPR;
    if (gr < N) {
        if (l16 < H) {
            float pv = (l16 == 0) ? ps0 : (l16 == 1) ? ps1 : (l16 == 2) ? ps2 : ps3;
            float dv = (l16 == 0) ? pd0 : (l16 == 1) ? pd1 : (l16 == 2) ? pd2 : pd3;
            a_src[gr * H + l16] = pv;
            a_dst[gr * H + l16] = dv;
        }
        #pragma unroll
        for (int g = 0; g < NG; ++g) {
            size_t idx = (size_t)gr * FOUT + cb + g * (TPR * 4);
            const float* ap = (const float*)&acc[g];
            ushort4 o;
            o.x = f2bf(ap[0]); o.y = f2bf(ap[1]); o.z = f2bf(ap[2]); o.w = f2bf(ap[3]);
            *(ushort4*)(Hout + idx) = o;
        }
    }
}

// ---------------------------------------------------------------- fused aggregation (bf16 h)
// One wave per dst node; single-pass softmax (shift c=max(a_dst,0), exact).
// Phase A: per-edge weights -> LDS. Phase B: 8B/lane gather (4 bf16), EPI edges/iter.
// FUSE3: epilogue computes h3 = row@W3 + attn3 dots -> h3x4[n] (replaces gemm3+attn3; no obuf write).
template<int H, int C, bool ELU, bool FUSE3>
__global__ __launch_bounds__(256) void agg_fused_kernel(
        const unsigned short* __restrict__ Hb, const float* __restrict__ a_src,
        const float* __restrict__ a_dst, const int* __restrict__ row_ptr,
        const unsigned short* __restrict__ colw, const float* __restrict__ bias,
        float* __restrict__ out, const float* __restrict__ W3,
        const float* __restrict__ as3, const float* __restrict__ ad3,
        float* __restrict__ h3x4, int N) {
    constexpr int HC  = H * C;
    constexpr int LPW = HC / 4;       // lanes per edge (4 bf16 = 8B each)
    constexpr int EPI = 64 / LPW;     // edges per inner iteration (2 or 4)
    constexpr int SHIFT = (HC == 128) ? 8 : 7;
    static_assert(HC == 128 || HC == 64, "layout");
    __shared__ float sP[4][64 * H];
    __shared__ int   sS[4][64];
    int wv   = threadIdx.x >> 6;
    int lane = threadIdx.x & 63;
    int n = (int)(blockIdx.x * 4 + wv);
    if (n >= N) return;
    int start = row_ptr[n];
    int deg   = row_ptr[n + 1] - start;

    float adv[H], cc[H], sp[H];
    #pragma unroll
    for (int h = 0; h < H; ++h) {
        adv[h] = a_dst[n * H + h];
        cc[h]  = fmaxf(adv[h], 0.f);
        sp[h]  = 0.f;
    }

    int sub = lane / LPW, pl = lane % LPW;
    int elem0 = pl * 4;               // 4 elems, same head (C=32)
    int hh = elem0 / C;
    float a0 = 0.f, a1 = 0.f, a2 = 0.f, a3 = 0.f;

    for (int base = 0; base <= deg; base += 64) {
        int cnt = min(64, deg + 1 - base);
        int idx = base + lane;
        if (idx <= deg) {
            int src = (idx < deg) ? (int)colw[start + idx] : n;
            sS[wv][lane] = src;
            float av[H];
            if constexpr (H == 4) {
                float4 t = *(const float4*)&a_src[src * 4];
                av[0] = t.x; av[1] = t.y; av[2] = t.z; av[3] = t.w;
            } else {
                float2 t = *(const float2*)&a_src[src * 2];
                av[0] = t.x; av[1] = t.y;
            }
            #pragma unroll
            for (int h = 0; h < H; ++h) {
                float e = av[h] + adv[h];
                e = (e >= 0.f) ? e : NEG_SLOPE * e;
                float p = __expf(e - cc[h]);
                sp[h] += p;
                sP[wv][lane * H + h] = p;
            }
        }
        __threadfence_block();
        #pragma unroll 4
        for (int k = 0; k < cnt; k += EPI) {
            int eidx = k + sub;
            int eclm = min(eidx, cnt - 1);
            float w  = sP[wv][eclm * H + hh];
            int  src = sS[wv][eclm];
            if (eidx >= cnt) w = 0.f;
            const char* pb = (const char*)Hb + (((size_t)src) << SHIFT) + elem0 * 2;
            uint2 pv = *(const uint2*)pb;
            a0 = fmaf(w, bf_lo(pv.x), a0);
            a1 = fmaf(w, bf_hi(pv.x), a1);
            a2 = fmaf(w, bf_lo(pv.y), a2);
            a3 = fmaf(w, bf_hi(pv.y), a3);
        }
        __threadfence_block();
    }

    #pragma unroll
    for (int off = 32; off; off >>= 1) {
        #pragma unroll
        for (int h = 0; h < H; ++h) sp[h] += __shfl_xor(sp[h], off);
    }
    // butterfly over sub-groups: all lanes end with full sums
    #pragma unroll
    for (int off = 32; off >= LPW; off >>= 1) {
        a0 += __shfl_xor(a0, off); a1 += __shfl_xor(a1, off);
        a2 += __shfl_xor(a2, off); a3 += __shfl_xor(a3, off);
    }
    float inv = 1.f / sp[hh];
    float4 b4 = *(const float4*)&bias[elem0];
    float v0 = a0 * inv + b4.x, v1 = a1 * inv + b4.y;
    float v2 = a2 * inv + b4.z, v3 = a3 * inv + b4.w;
    if (ELU) {
        v0 = (v0 > 0.f) ? v0 : __expf(v0) - 1.f;
        v1 = (v1 > 0.f) ? v1 : __expf(v1) - 1.f;
        v2 = (v2 > 0.f) ? v2 : __expf(v2) - 1.f;
        v3 = (v3 > 0.f) ? v3 : __expf(v3) - 1.f;
    }
    if constexpr (!FUSE3) {
        if (sub == 0)
            *(float4*)&out[(size_t)n * HC + elem0] = make_float4(v0, v1, v2, v3);
    } else {
        // h3 = row @ W3 (64x2); attn3 dots; write {h0,h1,as,ad}
        float p0 = v0 * W3[elem0 * 2]     + v1 * W3[elem0 * 2 + 2]
                 + v2 * W3[elem0 * 2 + 4] + v3 * W3[elem0 * 2 + 6];
        float p1 = v0 * W3[elem0 * 2 + 1] + v1 * W3[elem0 * 2 + 3]
                 + v2 * W3[elem0 * 2 + 5] + v3 * W3[elem0 * 2 + 7];
        #pragma unroll
        for (int off = 1; off < 16; off <<= 1) {
            p0 += __shfl_xor(p0, off);
            p1 += __shfl_xor(p1, off);
        }
        if (lane == 0) {
            float as = p0 * as3[0] + p1 * as3[1];
            float ad = p0 * ad3[0] + p1 * ad3[1];
            *(float4*)&h3x4[(size_t)n * 4] = make_float4(p0, p1, as, ad);
        }
    }
}

// layer 3: single 16B gather {h0,h1,as,ad}; bias + log_softmax -> d_out
__global__ __launch_bounds__(256) void agg3_kernel(
        const float* __restrict__ h3x4, const int* __restrict__ row_ptr,
        const unsigned short* __restrict__ colw, const float* __restrict__ bias,
        float* __restrict__ out, int N) {
    int wave = (int)((blockIdx.x * blockDim.x + threadIdx.x) >> 6);
    int lane = threadIdx.x & 63;
    if (wave >= N) return;
    int n = wave;
    int start = row_ptr[n];
    int deg   = row_ptr[n + 1] - start;
    float adv = h3x4[(size_t)n * 4 + 3];
    float c   = fmaxf(adv, 0.f);
    float s = 0.f, acc0 = 0.f, acc1 = 0.f;
    for (int i = lane; i <= deg; i += 64) {
        int src = (i < deg) ? (int)colw[start + i] : n;
        float4 g = *(const float4*)&h3x4[(size_t)src * 4];
        float e = g.z + adv;
        e = (e >= 0.f) ? e : NEG_SLOPE * e;
        float p = __expf(e - c);
        s += p;
        acc0 = fmaf(p, g.x, acc0);
        acc1 = fmaf(p, g.y, acc1);
    }
    #pragma unroll
    for (int off = 32; off; off >>= 1) {
        s    += __shfl_xor(s, off);
        acc0 += __shfl_xor(acc0, off);
        acc1 += __shfl_xor(acc1, off);
    }
    if (lane == 0) {
        float v0 = acc0 / s + bias[0];
        float v1 = acc1 / s + bias[1];
        float mx = fmaxf(v0, v1);
        float lse = mx + logf(__expf(v0 - mx) + __expf(v1 - mx));
        out[n * 2 + 0] = v0 - lse;
        out[n * 2 + 1] = v1 - lse;
    }
}

// ---------------------------------------------------------------- launch
extern "C" void kernel_launch(void* const* d_in, const int* in_sizes, int n_in,
                              void* d_out, int out_size, void* d_ws, size_t ws_size,
                              hipStream_t stream) {
    const float* x   = (const float*)d_in[0];
    const int*   ei  = (const int*)d_in[1];
    const float* W1  = (const float*)d_in[2];
    const float* as1 = (const float*)d_in[3];
    const float* ad1 = (const float*)d_in[4];
    const float* b1  = (const float*)d_in[5];
    const float* W2  = (const float*)d_in[6];
    const float* as2 = (const float*)d_in[7];
    const float* ad2 = (const float*)d_in[8];
    const float* b2  = (const float*)d_in[9];
    const float* W3  = (const float*)d_in[10];
    const float* as3 = (const float*)d_in[11];
    const float* ad3 = (const float*)d_in[12];
    const float* b3  = (const float*)d_in[13];
    int N = in_sizes[0] / 128;
    int E = in_sizes[1] / 2;
    const int* src = ei;
    const int* dst = ei + E;
    int NB = (N + 255) / 256;

    char* ws = (char*)d_ws;
    size_t off = 0;
    auto alloc = [&](size_t bytes) -> void* {
        void* p = ws + off;
        off = (off + bytes + 255) & ~(size_t)255;
        return p;
    };
    int*            bcnt    = (int*)alloc(256 * 4);
    int*            bbase   = (int*)alloc(257 * 4);
    int*            bcur    = (int*)alloc(256 * 4);
    int*            row_ptr = (int*)alloc((size_t)(N + 1) * 4);
    uint32_t*       packed  = (uint32_t*)alloc((size_t)E * 4);
    unsigned short* colw    = (unsigned short*)alloc((size_t)E * 2);
    unsigned short* hb      = (unsigned short*)alloc((size_t)N * 128 * 2);
    float*          obuf    = (float*)alloc((size_t)N * 128 * 4);   // layer-1 output (fp32)
    float*          h3x4    = (float*)alloc((size_t)N * 4 * 4);     // {h0,h1,as,ad}
    float*          asrc    = (float*)alloc((size_t)N * 4 * 4);
    float*          adst    = (float*)alloc((size_t)N * 4 * 4);
    int*            mflag   = (int*)alloc(4);
    unsigned short* Wp1     = (unsigned short*)alloc((size_t)2 * 4 * 8 * 512 * 2);
    unsigned short* Wp2     = (unsigned short*)alloc((size_t)2 * 4 * 4 * 512 * 2);

    // MFMA layout probe + W fragment pre-pack
    mfma_probe_kernel<<<1, 64, 0, stream>>>(mflag);
    packW_kernel<128, 128><<<8, 256, 0, stream>>>(W1, Wp1, mflag);
    packW_kernel<128, 64><<<4, 256, 0, stream>>>(W2, Wp2, mflag);

    // CSR by dst via 2-level bucket sort
    hipMemsetAsync(bcnt, 0, 256 * 4, stream);
    bkt_count_kernel<<<256, 256, 0, stream>>>(dst, bcnt, E);
    bkt_scan_kernel<<<1, 256, 0, stream>>>(bcnt, bbase, bcur, row_ptr, N, E);
    bkt_scatter_kernel<<<256, 256, 0, stream>>>(src, dst, bcur, packed, E);
    bkt_sort_kernel<<<NB, 256, 0, stream>>>(packed, bbase, row_ptr, colw, N);

    int gmblocks = ((N + 15) / 16 + 3) / 4;

    // layer 1: 128 -> 4x32 (concat), elu  [gemm + attn fused]
    gemm_mfma_kernel<128, 128, 4><<<gmblocks, 256, 0, stream>>>(x, Wp1, hb, asrc, adst, as1, ad1, mflag, N);
    gemm_fb_kernel<128, 128, 16, 4><<<(N + 15) / 16, 256, 0, stream>>>(x, W1, hb, asrc, adst, as1, ad1, mflag, N);
    agg_fused_kernel<4, 32, true, false><<<(N + 3) / 4, 256, 0, stream>>>(
        hb, asrc, adst, row_ptr, colw, b1, obuf, nullptr, nullptr, nullptr, nullptr, N);

    // layer 2: 128 -> 2x32 (concat), elu  [gemm + attn fused; agg + gemm3 + attn3 fused]
    gemm_mfma_kernel<128, 64, 2><<<gmblocks, 256, 0, stream>>>(obuf, Wp2, hb, asrc, adst, as2, ad2, mflag, N);
    gemm_fb_kernel<128, 64, 16, 2><<<(N + 15) / 16, 256, 0, stream>>>(obuf, W2, hb, asrc, adst, as2, ad2, mflag, N);
    agg_fused_kernel<2, 32, true, true><<<(N + 3) / 4, 256, 0, stream>>>(
        hb, asrc, adst, row_ptr, colw, b2, nullptr, W3, as3, ad3, h3x4, N);

    // layer 3: aggregation + bias + log_softmax
    agg3_kernel<<<(N + 3) / 4, 256, 0, stream>>>(h3x4, row_ptr, colw, b3, (float*)d_out, N);
}

// Round 8
// 203.229 us; speedup vs baseline: 2.0961x; 1.0897x over previous
//
#include <hip/hip_runtime.h>
#include <hip/hip_bf16.h>

#define NEG_SLOPE 0.2f
#define ARENA 10240   // per-bucket arena slots; mean load 8163, sigma~90 -> no overflow

typedef __attribute__((ext_vector_type(8))) short short8v;
typedef __attribute__((ext_vector_type(4))) float f32x4;

// ---------------------------------------------------------------- bf16 helpers
__device__ __forceinline__ float bf_lo(uint32_t u) { return __uint_as_float(u << 16); }
__device__ __forceinline__ float bf_hi(uint32_t u) { return __uint_as_float(u & 0xffff0000u); }
__device__ __forceinline__ unsigned short f2bf(float f) {
    uint32_t u = __float_as_uint(f);
    u += 0x7fffu + ((u >> 16) & 1u);   // round-to-nearest-even
    return (unsigned short)(u >> 16);
}
__device__ __forceinline__ float bf2f(unsigned short h) {
    return __uint_as_float((uint32_t)h << 16);
}

// (lane,reg)->k map for mfma_f32_16x16x32_bf16 A/B operands (validated on-target
// R6/R7: any consistent A/B bijection cancels; C/D map is m89 HW-verified).
__device__ __forceinline__ int k_of(int l, int j) {
    return (l >> 4) * 4 + (j & 3) + 16 * (j >> 2);
}

// pack W[FIN][FOUT] into fragment order: [plane(hi/lo)][q][nt][lane][j] bf16
template<int FIN, int FOUT>
__global__ void packW_kernel(const float* __restrict__ W, unsigned short* __restrict__ Wp) {
    constexpr int NT = FOUT / 16, KC = FIN / 32;
    int tid = blockIdx.x * blockDim.x + threadIdx.x;
    if (tid >= KC * NT * 64) return;
    int l  = tid & 63;
    int nt = (tid >> 6) % NT;
    int q  = tid / (64 * NT);
    int n  = nt * 16 + (l & 15);
    #pragma unroll
    for (int j = 0; j < 8; ++j) {
        int k = q * 32 + k_of(l, j);
        float v = W[k * FOUT + n];
        unsigned short h = f2bf(v);
        unsigned short lo = f2bf(v - bf2f(h));
        Wp[(((size_t)0 * KC + q) * NT + nt) * 512 + l * 8 + j] = h;
        Wp[(((size_t)1 * KC + q) * NT + nt) * 512 + l * 8 + j] = lo;
    }
}

// MFMA GEMM + fused attention-dot epilogue. X fp32 -> Hout bf16; split-bf16 x3.
template<int FIN, int FOUT, int H>
__global__ __launch_bounds__(256) void gemm_mfma_kernel(const float* __restrict__ X,
        const unsigned short* __restrict__ Wp, unsigned short* __restrict__ Hout,
        float* __restrict__ a_src, float* __restrict__ a_dst,
        const float* __restrict__ att_s, const float* __restrict__ att_d, int N) {
    constexpr int NT = FOUT / 16, KC = FIN / 32;
    __shared__ float sX[4][16 * FIN];
    int wv = threadIdx.x >> 6, l = threadIdx.x & 63;
    int mtile = blockIdx.x * 4 + wv;
    if (mtile * 16 >= N) return;          // N % 16 == 0 here
    const float* xsrc = X + (size_t)mtile * 16 * FIN;
    float* lds = sX[wv];
    #pragma unroll
    for (int i = 0; i < (16 * FIN) / 256; ++i) {
        int fi = (i * 64 + l) * 4;
        *(float4*)&lds[fi] = *(const float4*)&xsrc[fi];
    }
    __threadfence_block();

    int koff[8];
    #pragma unroll
    for (int j = 0; j < 8; ++j) koff[j] = k_of(l, j);
    int arow = (l & 15) * FIN;

    f32x4 acc[NT];
    #pragma unroll
    for (int nt = 0; nt < NT; ++nt) acc[nt] = f32x4{0.f, 0.f, 0.f, 0.f};

    const short8v* wp8 = (const short8v*)Wp;
    for (int q = 0; q < KC; ++q) {
        short8v ahi, alo;
        #pragma unroll
        for (int j = 0; j < 8; ++j) {
            float v = lds[arow + q * 32 + koff[j]];
            unsigned short h = f2bf(v);
            ahi[j] = (short)h;
            alo[j] = (short)f2bf(v - bf2f(h));
        }
        #pragma unroll
        for (int nt = 0; nt < NT; ++nt) {
            short8v bhi = wp8[((0 * KC + q) * NT + nt) * 64 + l];
            short8v blo = wp8[((1 * KC + q) * NT + nt) * 64 + l];
            acc[nt] = __builtin_amdgcn_mfma_f32_16x16x32_bf16(ahi, bhi, acc[nt], 0, 0, 0);
            acc[nt] = __builtin_amdgcn_mfma_f32_16x16x32_bf16(alo, bhi, acc[nt], 0, 0, 0);
            acc[nt] = __builtin_amdgcn_mfma_f32_16x16x32_bf16(ahi, blo, acc[nt], 0, 0, 0);
        }
    }

    // epilogue 1: attention dots (head = nt>>1, C=32); LDS transpose-reduce
    float as_v[NT], ad_v[NT];
    #pragma unroll
    for (int nt = 0; nt < NT; ++nt) {
        as_v[nt] = att_s[nt * 16 + (l & 15)];
        ad_v[nt] = att_d[nt * 16 + (l & 15)];
    }
    float ps[4][H], pd[4][H];
    #pragma unroll
    for (int r = 0; r < 4; ++r)
        #pragma unroll
        for (int h = 0; h < H; ++h) { ps[r][h] = 0.f; pd[r][h] = 0.f; }
    #pragma unroll
    for (int nt = 0; nt < NT; ++nt)
        #pragma unroll
        for (int r = 0; r < 4; ++r) {
            ps[r][nt >> 1] += acc[nt][r] * as_v[nt];
            pd[r][nt >> 1] += acc[nt][r] * ad_v[nt];
        }
    constexpr int V = 4 * H;
    float* sc = lds;
    int g = l >> 4, l16 = l & 15;
    int base = g * 16 * V + l16 * V;
    __threadfence_block();
    #pragma unroll
    for (int r = 0; r < 4; ++r)
        #pragma unroll
        for (int h = 0; h < H; ++h) {
            sc[base + r * H + h]        = ps[r][h];
            sc[1024 + base + r * H + h] = pd[r][h];
        }
    __threadfence_block();
    if (l16 < V) {
        float S = 0.f, D = 0.f;
        #pragma unroll
        for (int x = 0; x < 16; ++x) {
            S += sc[g * 16 * V + x * V + l16];
            D += sc[1024 + g * 16 * V + x * V + l16];
        }
        int r = l16 / H, h = l16 % H;
        int row = mtile * 16 + g * 4 + r;
        a_src[row * H + h] = S;
        a_dst[row * H + h] = D;
    }

    // epilogue 2: bf16 H output
    int row0 = mtile * 16 + (l >> 4) * 4;
    int col  = l & 15;
    #pragma unroll
    for (int nt = 0; nt < NT; ++nt)
        #pragma unroll
        for (int r = 0; r < 4; ++r)
            Hout[(size_t)(row0 + r) * FOUT + nt * 16 + col] = f2bf(acc[nt][r]);
}

// ---------------------------------------------------------------- CSR build (arena bucket sort)
// bucket = dst>>8; fixed arenas (no count/scan passes). All writes block-owned.
__global__ void arena_init_kernel(int* __restrict__ bcur) {
    bcur[threadIdx.x] = threadIdx.x * ARENA;
}

__global__ __launch_bounds__(256) void bkt_scatter_kernel(const int* __restrict__ src,
        const int* __restrict__ dst, int* __restrict__ bcur,
        uint32_t* __restrict__ packed, int E) {
    __shared__ int lh[256], lbase[256], lcur[256];
    int tid = threadIdx.x;
    lh[tid] = 0; lcur[tid] = 0;
    __syncthreads();
    int chunk = (E + gridDim.x - 1) / gridDim.x;
    int e0 = blockIdx.x * chunk;
    int e1 = min(E, e0 + chunk);
    for (int e = e0 + tid; e < e1; e += 256)
        atomicAdd(&lh[dst[e] >> 8], 1);
    __syncthreads();
    if (lh[tid]) lbase[tid] = atomicAdd(&bcur[tid], lh[tid]);
    __syncthreads();
    for (int e = e0 + tid; e < e1; e += 256) {
        int d = dst[e];
        int b = d >> 8;
        int pos = lbase[b] + atomicAdd(&lcur[b], 1);
        packed[pos] = ((uint32_t)(d & 255) << 16) | (uint32_t)src[e];
    }
}

// one block per bucket: counting sort by low byte; emits row_ptr (arena coords) + deg
__global__ __launch_bounds__(256) void bkt_sort_kernel(const uint32_t* __restrict__ packed,
        const int* __restrict__ bcur, int* __restrict__ row_ptr, int* __restrict__ degA,
        unsigned short* __restrict__ colw, int N) {
    __shared__ int lh[256], lexcl[256], lcur[256];
    __shared__ int ws4[4];
    int tid = threadIdx.x, lane = tid & 63, wid = tid >> 6;
    int B = blockIdx.x;
    int seg0 = B * ARENA, seg1 = bcur[B];
    lh[tid] = 0; lcur[tid] = 0;
    __syncthreads();
    for (int i = seg0 + tid; i < seg1; i += 256)
        atomicAdd(&lh[packed[i] >> 16], 1);
    __syncthreads();
    int v = lh[tid];
    int x = v;
    #pragma unroll
    for (int off = 1; off < 64; off <<= 1) {
        int t = __shfl_up(x, off);
        if (lane >= off) x += t;
    }
    if (lane == 63) ws4[wid] = x;
    __syncthreads();
    int add = 0;
    #pragma unroll
    for (int w = 0; w < 4; ++w) if (w < wid) add += ws4[w];
    int excl = add + x - v;
    lexcl[tid] = excl;
    int d = B * 256 + tid;
    if (d < N) { row_ptr[d] = seg0 + excl; degA[d] = v; }
    __syncthreads();
    for (int i = seg0 + tid; i < seg1; i += 256) {
        uint32_t p = packed[i];
        int bin = p >> 16;
        int pos = seg0 + lexcl[bin] + atomicAdd(&lcur[bin], 1);
        colw[pos] = (unsigned short)(p & 0xFFFF);
    }
}

// ---------------------------------------------------------------- fused aggregation (bf16 h)
// One wave per dst node; single-pass softmax (shift c=max(a_dst,0), exact).
// Phase A: per-edge weights -> LDS. Phase B: 16B/lane gather (8 bf16), EPI edges/iter.
// FUSE3: epilogue computes h3 = row@W3 + attn3 dots -> h3x4[n].
template<int H, int C, bool ELU, bool FUSE3>
__global__ __launch_bounds__(256) void agg_fused_kernel(
        const unsigned short* __restrict__ Hb, const float* __restrict__ a_src,
        const float* __restrict__ a_dst, const int* __restrict__ row_ptr,
        const int* __restrict__ degA, const unsigned short* __restrict__ colw,
        const float* __restrict__ bias, float* __restrict__ out,
        const float* __restrict__ W3, const float* __restrict__ as3,
        const float* __restrict__ ad3, float* __restrict__ h3x4, int N) {
    constexpr int HC  = H * C;
    constexpr int LPW = HC / 8;       // lanes per edge (8 bf16 = 16B each)
    constexpr int EPI = 64 / LPW;     // edges per inner iteration (4 or 8)
    constexpr int SHIFT = (HC == 128) ? 8 : 7;
    static_assert(HC == 128 || HC == 64, "layout");
    __shared__ float sP[4][64 * H];
    __shared__ int   sS[4][64];
    int wv   = threadIdx.x >> 6;
    int lane = threadIdx.x & 63;
    int n = (int)(blockIdx.x * 4 + wv);
    if (n >= N) return;
    int start = row_ptr[n];
    int deg   = degA[n];

    float adv[H], cc[H], sp[H];
    #pragma unroll
    for (int h = 0; h < H; ++h) {
        adv[h] = a_dst[n * H + h];
        cc[h]  = fmaxf(adv[h], 0.f);
        sp[h]  = 0.f;
    }

    int sub = lane / LPW, pl = lane % LPW;
    int elem0 = pl * 8;               // 8 elems, same head (C=32)
    int hh = elem0 / C;
    float a[8];
    #pragma unroll
    for (int j = 0; j < 8; ++j) a[j] = 0.f;

    for (int base = 0; base <= deg; base += 64) {
        int cnt = min(64, deg + 1 - base);
        int idx = base + lane;
        if (idx <= deg) {
            int srcn = (idx < deg) ? (int)colw[start + idx] : n;
            sS[wv][lane] = srcn;
            float av[H];
            if constexpr (H == 4) {
                float4 t = *(const float4*)&a_src[srcn * 4];
                av[0] = t.x; av[1] = t.y; av[2] = t.z; av[3] = t.w;
            } else {
                float2 t = *(const float2*)&a_src[srcn * 2];
                av[0] = t.x; av[1] = t.y;
            }
            #pragma unroll
            for (int h = 0; h < H; ++h) {
                float e = av[h] + adv[h];
                e = (e >= 0.f) ? e : NEG_SLOPE * e;
                float p = __expf(e - cc[h]);
                sp[h] += p;
                sP[wv][lane * H + h] = p;
            }
        }
        __threadfence_block();   // LDS writes visible (same wave, lockstep)
        #pragma unroll 4
        for (int k = 0; k < cnt; k += EPI) {
            int eidx = k + sub;
            int eclm = min(eidx, cnt - 1);
            float w  = sP[wv][eclm * H + hh];
            int srcn = sS[wv][eclm];
            if (eidx >= cnt) w = 0.f;
            const char* pb = (const char*)Hb + (((size_t)srcn) << SHIFT) + elem0 * 2;
            uint4 pv = *(const uint4*)pb;
            a[0] = fmaf(w, bf_lo(pv.x), a[0]);
            a[1] = fmaf(w, bf_hi(pv.x), a[1]);
            a[2] = fmaf(w, bf_lo(pv.y), a[2]);
            a[3] = fmaf(w, bf_hi(pv.y), a[3]);
            a[4] = fmaf(w, bf_lo(pv.z), a[4]);
            a[5] = fmaf(w, bf_hi(pv.z), a[5]);
            a[6] = fmaf(w, bf_lo(pv.w), a[6]);
            a[7] = fmaf(w, bf_hi(pv.w), a[7]);
        }
        __threadfence_block();   // reads done before next chunk overwrites
    }

    #pragma unroll
    for (int off = 32; off; off >>= 1) {
        #pragma unroll
        for (int h = 0; h < H; ++h) sp[h] += __shfl_xor(sp[h], off);
    }
    // butterfly over edge-subgroups: all lanes end with full sums
    #pragma unroll
    for (int off = 32; off >= LPW; off >>= 1) {
        #pragma unroll
        for (int j = 0; j < 8; ++j) a[j] += __shfl_xor(a[j], off);
    }
    float inv = 1.f / sp[hh];
    float v[8];
    float4 b40 = *(const float4*)&bias[elem0];
    float4 b41 = *(const float4*)&bias[elem0 + 4];
    v[0] = a[0] * inv + b40.x; v[1] = a[1] * inv + b40.y;
    v[2] = a[2] * inv + b40.z; v[3] = a[3] * inv + b40.w;
    v[4] = a[4] * inv + b41.x; v[5] = a[5] * inv + b41.y;
    v[6] = a[6] * inv + b41.z; v[7] = a[7] * inv + b41.w;
    if (ELU) {
        #pragma unroll
        for (int j = 0; j < 8; ++j) v[j] = (v[j] > 0.f) ? v[j] : __expf(v[j]) - 1.f;
    }
    if constexpr (!FUSE3) {
        if (sub == 0) {
            *(float4*)&out[(size_t)n * HC + elem0]     = make_float4(v[0], v[1], v[2], v[3]);
            *(float4*)&out[(size_t)n * HC + elem0 + 4] = make_float4(v[4], v[5], v[6], v[7]);
        }
    } else {
        // h3 = row @ W3 (64x2); attn3 dots; write {h0,h1,as,ad}
        float p0 = 0.f, p1 = 0.f;
        #pragma unroll
        for (int j = 0; j < 8; ++j) {
            p0 += v[j] * W3[(elem0 + j) * 2];
            p1 += v[j] * W3[(elem0 + j) * 2 + 1];
        }
        #pragma unroll
        for (int off = 4; off; off >>= 1) {
            p0 += __shfl_xor(p0, off);
            p1 += __shfl_xor(p1, off);
        }
        if (lane == 0) {
            float as = p0 * as3[0] + p1 * as3[1];
            float ad = p0 * ad3[0] + p1 * ad3[1];
            *(float4*)&h3x4[(size_t)n * 4] = make_float4(p0, p1, as, ad);
        }
    }
}

// layer 3: single 16B gather {h0,h1,as,ad}; bias + log_softmax -> d_out
__global__ __launch_bounds__(256) void agg3_kernel(
        const float* __restrict__ h3x4, const int* __restrict__ row_ptr,
        const int* __restrict__ degA, const unsigned short* __restrict__ colw,
        const float* __restrict__ bias, float* __restrict__ out, int N) {
    int wave = (int)((blockIdx.x * blockDim.x + threadIdx.x) >> 6);
    int lane = threadIdx.x & 63;
    if (wave >= N) return;
    int n = wave;
    int start = row_ptr[n];
    int deg   = degA[n];
    float adv = h3x4[(size_t)n * 4 + 3];
    float c   = fmaxf(adv, 0.f);
    float s = 0.f, acc0 = 0.f, acc1 = 0.f;
    for (int i = lane; i <= deg; i += 64) {
        int srcn = (i < deg) ? (int)colw[start + i] : n;
        float4 g = *(const float4*)&h3x4[(size_t)srcn * 4];
        float e = g.z + adv;
        e = (e >= 0.f) ? e : NEG_SLOPE * e;
        float p = __expf(e - c);
        s += p;
        acc0 = fmaf(p, g.x, acc0);
        acc1 = fmaf(p, g.y, acc1);
    }
    #pragma unroll
    for (int off = 32; off; off >>= 1) {
        s    += __shfl_xor(s, off);
        acc0 += __shfl_xor(acc0, off);
        acc1 += __shfl_xor(acc1, off);
    }
    if (lane == 0) {
        float v0 = acc0 / s + bias[0];
        float v1 = acc1 / s + bias[1];
        float mx = fmaxf(v0, v1);
        float lse = mx + logf(__expf(v0 - mx) + __expf(v1 - mx));
        out[n * 2 + 0] = v0 - lse;
        out[n * 2 + 1] = v1 - lse;
    }
}

// ---------------------------------------------------------------- launch
extern "C" void kernel_launch(void* const* d_in, const int* in_sizes, int n_in,
                              void* d_out, int out_size, void* d_ws, size_t ws_size,
                              hipStream_t stream) {
    const float* x   = (const float*)d_in[0];
    const int*   ei  = (const int*)d_in[1];
    const float* W1  = (const float*)d_in[2];
    const float* as1 = (const float*)d_in[3];
    const float* ad1 = (const float*)d_in[4];
    const float* b1  = (const float*)d_in[5];
    const float* W2  = (const float*)d_in[6];
    const float* as2 = (const float*)d_in[7];
    const float* ad2 = (const float*)d_in[8];
    const float* b2  = (const float*)d_in[9];
    const float* W3  = (const float*)d_in[10];
    const float* as3 = (const float*)d_in[11];
    const float* ad3 = (const float*)d_in[12];
    const float* b3  = (const float*)d_in[13];
    int N = in_sizes[0] / 128;
    int E = in_sizes[1] / 2;
    const int* src = ei;
    const int* dst = ei + E;
    int NB = (N + 255) / 256;   // used buckets

    char* ws = (char*)d_ws;
    size_t off = 0;
    auto alloc = [&](size_t bytes) -> void* {
        void* p = ws + off;
        off = (off + bytes + 255) & ~(size_t)255;
        return p;
    };
    int*            bcur    = (int*)alloc(256 * 4);
    int*            row_ptr = (int*)alloc((size_t)N * 4);
    int*            degA    = (int*)alloc((size_t)N * 4);
    uint32_t*       packed  = (uint32_t*)alloc((size_t)NB * ARENA * 4);
    unsigned short* colw    = (unsigned short*)alloc((size_t)NB * ARENA * 2);
    unsigned short* hb      = (unsigned short*)alloc((size_t)N * 128 * 2);
    float*          obuf    = (float*)alloc((size_t)N * 128 * 4);   // layer-1 output (fp32)
    float*          h3x4    = (float*)alloc((size_t)N * 4 * 4);     // {h0,h1,as,ad}
    float*          asrc    = (float*)alloc((size_t)N * 4 * 4);
    float*          adst    = (float*)alloc((size_t)N * 4 * 4);
    unsigned short* Wp1     = (unsigned short*)alloc((size_t)2 * 4 * 8 * 512 * 2);
    unsigned short* Wp2     = (unsigned short*)alloc((size_t)2 * 4 * 4 * 512 * 2);

    // W fragment pre-pack (hi/lo split planes)
    packW_kernel<128, 128><<<8, 256, 0, stream>>>(W1, Wp1);
    packW_kernel<128, 64><<<4, 256, 0, stream>>>(W2, Wp2);

    // CSR by dst via arena bucket sort (3 kernels, no count/scan)
    arena_init_kernel<<<1, 256, 0, stream>>>(bcur);
    bkt_scatter_kernel<<<256, 256, 0, stream>>>(src, dst, bcur, packed, E);
    bkt_sort_kernel<<<NB, 256, 0, stream>>>(packed, bcur, row_ptr, degA, colw, N);

    int gmblocks = ((N + 15) / 16 + 3) / 4;

    // layer 1: 128 -> 4x32 (concat), elu  [gemm + attn fused]
    gemm_mfma_kernel<128, 128, 4><<<gmblocks, 256, 0, stream>>>(x, Wp1, hb, asrc, adst, as1, ad1, N);
    agg_fused_kernel<4, 32, true, false><<<(N + 3) / 4, 256, 0, stream>>>(
        hb, asrc, adst, row_ptr, degA, colw, b1, obuf, nullptr, nullptr, nullptr, nullptr, N);

    // layer 2: 128 -> 2x32 (concat), elu  [gemm + attn fused; agg + gemm3 + attn3 fused]
    gemm_mfma_kernel<128, 64, 2><<<gmblocks, 256, 0, stream>>>(obuf, Wp2, hb, asrc, adst, as2, ad2, N);
    agg_fused_kernel<2, 32, true, true><<<(N + 3) / 4, 256, 0, stream>>>(
        hb, asrc, adst, row_ptr, degA, colw, b2, nullptr, W3, as3, ad3, h3x4, N);

    // layer 3: aggregation + bias + log_softmax
    agg3_kernel<<<(N + 3) / 4, 256, 0, stream>>>(h3x4, row_ptr, degA, colw, b3, (float*)d_out, N);
}